// Round 3
// baseline (336.141 us; speedup 1.0000x reference)
//
#include <hip/hip_runtime.h>
#include <hip/hip_bf16.h>

// RoPEAttention B=2 S=2048 D=1024 H=16 HD=64, fp32 in/out.
// R12: flash_mfma -> drop LDS staging entirely (K/V per (bh,sp) = 256KB, all 16
//      q-blocks of a group pinned to one XCD -> L2-resident; LDS gave ZERO reuse:
//      each wave read each K/V element exactly once). Read MFMA fragments direct
//      from global: kf = K[key][quad*8], va = V^T[hd][kt+st*16+quad*4].
//      Removes 4.19M bank conflicts/dispatch, all barriers, rk/rv prefetch regs.
// R11: gemm_qkv 2-phase dbuf pipeline (kept).
// ws (shorts): qbh[0,4M) kbh[4M,8M) vt[8M,12M) xb[16M,20M)
//              wqkvb[20M,23M) wob[23M,24M) po[24M,32M) pl(fp32) after.

#define B_ 2
#define S_ 2048
#define D_ 1024
#define H_ 16
#define HD_ 64
#define M_ (B_*S_)
#define SPLIT_ 2
#define KSPAN_ (S_/SPLIT_)    // 1024 keys per split

typedef __attribute__((ext_vector_type(8))) short short8;
typedef __attribute__((ext_vector_type(4))) short short4v;
typedef __attribute__((ext_vector_type(4))) float f32x4;
typedef __attribute__((ext_vector_type(4))) _Float16 half4;
typedef __attribute__((ext_vector_type(8))) _Float16 half8;

static __device__ __forceinline__ short f2bf(float f) {
    __hip_bfloat16 h = __float2bfloat16(f);
    return *reinterpret_cast<short*>(&h);
}
static __device__ __forceinline__ short f2h(float f) {
    _Float16 h = (_Float16)f;
    return *reinterpret_cast<short*>(&h);
}

typedef __attribute__((address_space(1))) const unsigned int gu32_t;
typedef __attribute__((address_space(3))) unsigned int lu32_t;
static __device__ __forceinline__ void gld16(const short* g, short* l) {
    __builtin_amdgcn_global_load_lds((gu32_t*)g, (lu32_t*)l, 16, 0, 0);
}

// ---------------- fp32 -> bf16 convert: x, wq|wk|wv (concat), wo ----------------
__global__ __launch_bounds__(256)
void convert_bf16(const float* __restrict__ x,
                  const float* __restrict__ wq, const float* __restrict__ wk,
                  const float* __restrict__ wv, const float* __restrict__ wo,
                  short* __restrict__ xb, short* __restrict__ wqkvb, short* __restrict__ wob)
{
    const size_t t4 = ((size_t)blockIdx.x * 256 + threadIdx.x) * 4;
    const float* src; short* dst; size_t off, doff;
    if (t4 < 4194304)      { src = x;  dst = xb;    off = t4;           doff = t4; }
    else if (t4 < 5242880) { src = wq; dst = wqkvb; off = t4 - 4194304; doff = t4 - 4194304; }
    else if (t4 < 6291456) { src = wk; dst = wqkvb; off = t4 - 5242880; doff = t4 - 4194304; }
    else if (t4 < 7340032) { src = wv; dst = wqkvb; off = t4 - 6291456; doff = t4 - 4194304; }
    else                   { src = wo; dst = wob;   off = t4 - 7340032; doff = t4 - 7340032; }
    float4 v = *(const float4*)(src + off);
    short4v s = { f2bf(v.x), f2bf(v.y), f2bf(v.z), f2bf(v.w) };
    *(short4v*)(dst + doff) = s;
}

// ---------------- bf16 MFMA GEMM NT 128x128, BK=64 XOR-swizzled, 2-phase dbuf ----------------
// Epilogue: which==0/1 -> fused RMSNorm+RoPE -> Qb/Kb bf16 [B,H,S,HD]
//           which==2   -> Vt f16 [B,H,HD,S]
__global__ __launch_bounds__(256)
void gemm_qkv(const short* __restrict__ A, const short* __restrict__ Bw,
              short* __restrict__ Qb, short* __restrict__ Kb, short* __restrict__ Vt,
              const float* __restrict__ q_scale, const float* __restrict__ k_scale,
              const float* __restrict__ rope_cos, const float* __restrict__ rope_sin)
{
    __shared__ __align__(16) short As[2][128*64];   // 2 x 16KB
    __shared__ __align__(16) short Bs[2][128*64];   // 2 x 16KB  (total 64KB)
    const int tid = threadIdx.x;
    const int w = tid >> 6, lane = tid & 63, quad = lane >> 4, l16 = lane & 15;
    const int wr = w >> 1, wc = w & 1;
    const int bm0 = blockIdx.x * 128, bn0 = blockIdx.y * 128;

    // gld16 staging, 4 calls each for A/B. Call j stages slots p=j*256+tid:
    // row = p>>3 (=j*32 + tid>>3), kslot = p&7; slot holds chunk kch = kslot ^ (row&7).
    const int row_ = tid >> 3;
    const int kslot = tid & 7;
    const short* gA[4]; const short* gB[4];
    #pragma unroll
    for (int j = 0; j < 4; ++j) {
        const int row = j*32 + row_;
        const int kch = kslot ^ (row & 7);
        gA[j] = A  + (size_t)(bm0 + row) * 1024 + kch*8;
        gB[j] = Bw + (size_t)(bn0 + row) * 1024 + kch*8;
    }

    f32x4 acc[4][4];
    #pragma unroll
    for (int i = 0; i < 4; ++i)
        #pragma unroll
        for (int j = 0; j < 4; ++j) acc[i][j] = (f32x4){0.f,0.f,0.f,0.f};

    // prologue: stage K-tile 0 into buffer 0, drain, barrier
    #pragma unroll
    for (int j = 0; j < 4; ++j) {
        gld16(gA[j], &As[0][j*2048 + w*512]);
        gld16(gB[j], &Bs[0][j*2048 + w*512]);
    }
    asm volatile("s_waitcnt vmcnt(0)" ::: "memory");
    __builtin_amdgcn_s_barrier();
    __builtin_amdgcn_sched_barrier(0);

    int cur = 0;
    for (int t = 0; t < 16; ++t) {
        // issue next K-tile loads into the other buffer (stay in flight during MFMA)
        if (t < 15) {
            const int k0 = (t + 1) * 64;
            #pragma unroll
            for (int j = 0; j < 4; ++j) {
                gld16(gA[j] + k0, &As[cur ^ 1][j*2048 + w*512]);
                gld16(gB[j] + k0, &Bs[cur ^ 1][j*2048 + w*512]);
            }
        }
        __builtin_amdgcn_sched_barrier(0);

        short8 af[2][4], bfr[2][4];
        #pragma unroll
        for (int ph = 0; ph < 2; ++ph)
            #pragma unroll
            for (int i = 0; i < 4; ++i) {
                const int ra = wr*64 + i*16 + l16;
                af[ph][i]  = *(const short8*)(&As[cur][ra*64 + (((ph*4 + quad) ^ (ra & 7)) << 3)]);
                const int rb = wc*64 + i*16 + l16;
                bfr[ph][i] = *(const short8*)(&Bs[cur][rb*64 + (((ph*4 + quad) ^ (rb & 7)) << 3)]);
            }
        #pragma unroll
        for (int ph = 0; ph < 2; ++ph)
            #pragma unroll
            for (int i = 0; i < 4; ++i)
                #pragma unroll
                for (int j = 0; j < 4; ++j)
                    acc[i][j] = __builtin_amdgcn_mfma_f32_16x16x32_bf16(af[ph][i], bfr[ph][j], acc[i][j], 0, 0, 0);

        // wait own next-tile stores, then barrier: next iter's buffer is ready,
        // and all waves' reads of buf[cur] are done before anyone overwrites it.
        asm volatile("s_waitcnt vmcnt(0)" ::: "memory");
        __builtin_amdgcn_s_barrier();
        __builtin_amdgcn_sched_barrier(0);
        cur ^= 1;
    }

    // wave-uniform: this wave's 64 n-columns = one (which, head) pair
    const int nbase = bn0 + wc*64;
    const int which = nbase >> 10;
    const int h     = (nbase & 1023) >> 6;

    if (which < 2) {
        const float* sc = which ? k_scale : q_scale;
        short* dst      = which ? Kb : Qb;
        const float fold = which ? 1.0f : 0.18033688011112042f;  // q: (1/8)*log2(e)
        float scv[4];
        #pragma unroll
        for (int j = 0; j < 4; ++j) scv[j] = sc[j*16 + l16];
        #pragma unroll
        for (int i = 0; i < 4; ++i) {
            #pragma unroll
            for (int r = 0; r < 4; ++r) {
                const int m = bm0 + wr*64 + i*16 + quad*4 + r;
                const int b = m >> 11, s = m & (S_-1);
                float ss = 0.f;
                #pragma unroll
                for (int j = 0; j < 4; ++j) ss += acc[i][j][r] * acc[i][j][r];
                #pragma unroll
                for (int msk = 1; msk <= 8; msk <<= 1) ss += __shfl_xor(ss, msk, 64);
                const float rn = rsqrtf(ss * (1.0f/64.0f) + 1e-6f);
                #pragma unroll
                for (int j = 0; j < 4; ++j) {
                    const int hd = j*16 + l16;
                    const float nv = acc[i][j][r] * rn * scv[j];
                    const float c  = rope_cos[s*32 + (hd >> 1)];
                    const float sn = rope_sin[s*32 + (hd >> 1)];
                    const float partner = __shfl_xor(nv, 1, 64);
                    const float o = (hd & 1) ? (partner * sn + nv * c) : (nv * c - partner * sn);
                    dst[(((size_t)b*H_ + h)*S_ + s)*HD_ + hd] = f2bf(o * fold);
                }
            }
        }
    } else {
        #pragma unroll
        for (int i = 0; i < 4; ++i)
            #pragma unroll
            for (int r = 0; r < 4; ++r) {
                const int m = bm0 + wr*64 + i*16 + quad*4 + r;
                const int b = m >> 11, s = m & (S_-1);
                #pragma unroll
                for (int j = 0; j < 4; ++j) {
                    const int hd = j*16 + l16;
                    Vt[(((size_t)b*H_ + h)*HD_ + hd)*S_ + s] = f2h(acc[i][j][r]);
                }
            }
    }
}

// ---------------- out-proj GEMM 64x128, combine fused, po register-prefetch ----------------
__global__ __launch_bounds__(256)
void gemm_out(const short* __restrict__ po, const float* __restrict__ pl,
              const short* __restrict__ Bw, float* __restrict__ C)
{
    __shared__ __align__(16) short As[64*32];
    __shared__ __align__(16) short Bs[128*32];
    const int tid = threadIdx.x;
    const int w = tid >> 6, lane = tid & 63, quad = lane >> 4, l16 = lane & 15;
    const int bm0 = blockIdx.x * 64, bn0 = blockIdx.y * 128;

    const int srow = tid >> 2;
    const int skch = (tid & 3) * 8;
    const int m = bm0 + srow;
    const int b = m >> 11, s = m & (S_-1);
    const short* gB0 = Bw + (size_t)(bn0 + srow) * 1024 + skch;
    const short* gB1 = Bw + (size_t)(bn0 + 64 + srow) * 1024 + skch;
    short* lB0 = Bs + w*512;
    short* lB1 = Bs + 2048 + w*512;

    float inv[16];
    #pragma unroll
    for (int h = 0; h < 16; ++h)
        inv[h] = 1.0f / (pl[((size_t)(b*16 + h))*S_ + s] + pl[65536 + ((size_t)(b*16 + h))*S_ + s]);

    f32x4 acc[4][2];
    #pragma unroll
    for (int i = 0; i < 4; ++i) {
        acc[i][0] = (f32x4){0.f,0.f,0.f,0.f};
        acc[i][1] = (f32x4){0.f,0.f,0.f,0.f};
    }

    // prefetch k0=0 po chunks
    half8 c0 = *(const half8*)(po +            (size_t)m*1024 + skch);
    half8 c1 = *(const half8*)(po + 4194304 + (size_t)m*1024 + skch);

    for (int k0 = 0; k0 < 1024; k0 += 32) {
        const int h = k0 >> 6;          // head uniform per iter (skch+7 <= 31)
        short8 a;
        #pragma unroll
        for (int j = 0; j < 8; ++j)
            a[j] = f2bf(((float)c0[j] + (float)c1[j]) * inv[h]);
        __syncthreads();
        *(short8*)(As + srow*32 + skch) = a;
        gld16(gB0 + k0, lB0);
        gld16(gB1 + k0, lB1);
        __syncthreads();
        if (k0 < 1024 - 32) {           // issue next po loads before MFMA block
            c0 = *(const half8*)(po +            (size_t)m*1024 + k0 + 32 + skch);
            c1 = *(const half8*)(po + 4194304 + (size_t)m*1024 + k0 + 32 + skch);
        }
        short8 af[4], bfr[2];
        #pragma unroll
        for (int i = 0; i < 4; ++i)
            af[i] = *(const short8*)(As + (i*16 + l16)*32 + quad*8);
        #pragma unroll
        for (int j = 0; j < 2; ++j)
            bfr[j] = *(const short8*)(Bs + (w*32 + j*16 + l16)*32 + quad*8);
        #pragma unroll
        for (int i = 0; i < 4; ++i)
            #pragma unroll
            for (int j = 0; j < 2; ++j)
                acc[i][j] = __builtin_amdgcn_mfma_f32_16x16x32_bf16(af[i], bfr[j], acc[i][j], 0, 0, 0);
    }

    #pragma unroll
    for (int i = 0; i < 4; ++i)
        #pragma unroll
        for (int r = 0; r < 4; ++r) {
            const int mm = bm0 + i*16 + quad*4 + r;
            #pragma unroll
            for (int j = 0; j < 2; ++j) {
                const int n = bn0 + w*32 + j*16 + l16;
                C[(size_t)mm*1024 + n] = acc[i][j][r];
            }
        }
}

// ---------------- MFMA flash attention partial, split-K=2, direct-from-L2 (no LDS) ----------------
__global__ __launch_bounds__(256)
void flash_mfma(const short* __restrict__ qb, const short* __restrict__ kb,
                const short* __restrict__ vt, short* __restrict__ po, float* __restrict__ pl)
{
    const int id   = blockIdx.x;
    const int xcd  = id & 7;
    const int rest = id >> 3;
    const int qblk = rest & 15;               // 16 q-blocks of 128
    const int g    = (rest >> 4) * 8 + xcd;   // (bh,sp) group 0..63
    const int bh   = g >> 1;
    const int sp   = g & 1;

    const int tid  = threadIdx.x;
    const int wv   = tid >> 6;
    const int lane = tid & 63;
    const int quad = lane >> 4;
    const int l16  = lane & 15;
    const int b    = bh >> 4, h = bh & (H_-1);
    const int q0   = qblk * 128 + wv * 32;
    const int kt0  = sp * KSPAN_;
    const size_t hbase = (size_t)bh * S_ * HD_;
    const size_t vbase = (size_t)bh * HD_ * S_;
    short* po_sp = po + (size_t)sp * 4194304;
    float* pl_sp = pl + (size_t)sp * 65536;

    short8 qfrag[2][2];
    #pragma unroll
    for (int qf = 0; qf < 2; ++qf)
        #pragma unroll
        for (int c = 0; c < 2; ++c)
            qfrag[qf][c] = *(const short8*)(qb + hbase + (size_t)(q0 + qf*16 + l16)*HD_ + c*32 + quad*8);

    f32x4 Oacc[2][4];
    #pragma unroll
    for (int qf = 0; qf < 2; ++qf)
        #pragma unroll
        for (int dt = 0; dt < 4; ++dt) Oacc[qf][dt] = (f32x4){0.f,0.f,0.f,0.f};
    float l_lane[2] = {0.f, 0.f};

    const short* kp = kb + hbase;   // [key][hd=64]
    const short* vp = vt + vbase;   // [hd][key=2048] (f16 bits)

    #pragma unroll 1
    for (int t = 0; t < KSPAN_/64; ++t) {
        const int kt = kt0 + t*64;
        #pragma unroll
        for (int st = 0; st < 4; ++st) {
            const int key = kt + st*16 + l16;
            short8 kf0 = *(const short8*)(kp + (size_t)key*HD_ + quad*8);
            short8 kf1 = *(const short8*)(kp + (size_t)key*HD_ + 32 + quad*8);
            half4 va[4];
            #pragma unroll
            for (int dt = 0; dt < 4; ++dt)
                va[dt] = *(const half4*)(vp + (size_t)(dt*16 + l16)*S_ + kt + st*16 + quad*4);
            #pragma unroll
            for (int qf = 0; qf < 2; ++qf) {
                f32x4 acc = (f32x4){0.f,0.f,0.f,0.f};
                acc = __builtin_amdgcn_mfma_f32_16x16x32_bf16(kf0, qfrag[qf][0], acc, 0, 0, 0);
                acc = __builtin_amdgcn_mfma_f32_16x16x32_bf16(kf1, qfrag[qf][1], acc, 0, 0, 0);
                half4 pb;
                #pragma unroll
                for (int r = 0; r < 4; ++r) {
                    float p = __builtin_amdgcn_exp2f(acc[r] - 12.0f);
                    l_lane[qf] += p;
                    pb[r] = (_Float16)p;
                }
                #pragma unroll
                for (int dt = 0; dt < 4; ++dt)
                    Oacc[qf][dt] = __builtin_amdgcn_mfma_f32_16x16x16f16(va[dt], pb, Oacc[qf][dt], 0, 0, 0);
            }
        }
    }

    #pragma unroll
    for (int qf = 0; qf < 2; ++qf) {
        l_lane[qf] += __shfl_xor(l_lane[qf], 16, 64);
        l_lane[qf] += __shfl_xor(l_lane[qf], 32, 64);
        if (quad == 0) pl_sp[(size_t)bh*S_ + q0 + qf*16 + l16] = l_lane[qf];
    }
    #pragma unroll
    for (int qf = 0; qf < 2; ++qf) {
        const int s = q0 + qf*16 + l16;
        #pragma unroll
        for (int dt = 0; dt < 4; ++dt) {
            short4v o;
            #pragma unroll
            for (int r = 0; r < 4; ++r) o[r] = f2h(Oacc[qf][dt][r]);
            *(short4v*)(po_sp + (((size_t)b*S_ + s)*H_ + h)*HD_ + dt*16 + quad*4) = o;
        }
    }
}

extern "C" void kernel_launch(void* const* d_in, const int* in_sizes, int n_in,
                              void* d_out, int out_size, void* d_ws, size_t ws_size,
                              hipStream_t stream)
{
    (void)in_sizes; (void)n_in; (void)out_size; (void)ws_size;
    const float* x        = (const float*)d_in[0];
    const float* wq       = (const float*)d_in[1];
    const float* wk       = (const float*)d_in[2];
    const float* wv       = (const float*)d_in[3];
    const float* wo       = (const float*)d_in[4];
    const float* q_scale  = (const float*)d_in[5];
    const float* k_scale  = (const float*)d_in[6];
    const float* rope_cos = (const float*)d_in[7];
    const float* rope_sin = (const float*)d_in[8];
    float* out = (float*)d_out;
    short* ws  = (short*)d_ws;

    short* qbh   = ws;                 // 4M shorts
    short* kbh   = ws + 4194304;
    short* vt    = ws + 8388608;
    short* xb    = ws + 16777216;
    short* wqkvb = ws + 20971520;      // 3M shorts
    short* wob   = ws + 24117248;      // 1M shorts
    short* po    = ws + 25165824;      // 2 x 4M shorts (f16)
    float* pl    = (float*)(ws + 33554432);  // 2 x 64K floats

    convert_bf16<<<dim3(8192), 256, 0, stream>>>(x, wq, wk, wv, wo, xb, wqkvb, wob);
    gemm_qkv<<<dim3(M_/128, 24), 256, 0, stream>>>(xb, wqkvb, qbh, kbh, vt,
                                                   q_scale, k_scale, rope_cos, rope_sin);
    flash_mfma<<<dim3((S_/128)*B_*H_*SPLIT_), 256, 0, stream>>>(qbh, kbh, vt, po, pl);
    gemm_out<<<dim3(M_/64, D_/128), 256, 0, stream>>>(po, pl, wob, out);
}

// Round 4
// 214.723 us; speedup vs baseline: 1.5655x; 1.5655x over previous
//
#include <hip/hip_runtime.h>
#include <hip/hip_bf16.h>

// RoPEAttention B=2 S=2048 D=1024 H=16 HD=64, fp32 in/out.
// R13: revert R12's direct-from-L2 flash (3.3x regression: per-iter L2 latency
//      on critical path, latency-bound at MfmaUtil 11%). Back to R8/R2 LDS
//      staging + register prefetch, plus T5 s_setprio(1) around MFMA clusters
//      (independent 4-wave blocks at different phases -> scheduler arbitration pays).
// R11: gemm_qkv 2-phase dbuf pipeline (kept).
// ws (shorts): qbh[0,4M) kbh[4M,8M) vt[8M,12M) xb[16M,20M)
//              wqkvb[20M,23M) wob[23M,24M) po[24M,32M) pl(fp32) after.

#define B_ 2
#define S_ 2048
#define D_ 1024
#define H_ 16
#define HD_ 64
#define M_ (B_*S_)
#define SPLIT_ 2
#define KSPAN_ (S_/SPLIT_)    // 1024 keys per split

typedef __attribute__((ext_vector_type(8))) short short8;
typedef __attribute__((ext_vector_type(4))) short short4v;
typedef __attribute__((ext_vector_type(4))) float f32x4;
typedef __attribute__((ext_vector_type(4))) _Float16 half4;
typedef __attribute__((ext_vector_type(8))) _Float16 half8;

static __device__ __forceinline__ short f2bf(float f) {
    __hip_bfloat16 h = __float2bfloat16(f);
    return *reinterpret_cast<short*>(&h);
}
static __device__ __forceinline__ short f2h(float f) {
    _Float16 h = (_Float16)f;
    return *reinterpret_cast<short*>(&h);
}

typedef __attribute__((address_space(1))) const unsigned int gu32_t;
typedef __attribute__((address_space(3))) unsigned int lu32_t;
static __device__ __forceinline__ void gld16(const short* g, short* l) {
    __builtin_amdgcn_global_load_lds((gu32_t*)g, (lu32_t*)l, 16, 0, 0);
}

// ---------------- fp32 -> bf16 convert: x, wq|wk|wv (concat), wo ----------------
__global__ __launch_bounds__(256)
void convert_bf16(const float* __restrict__ x,
                  const float* __restrict__ wq, const float* __restrict__ wk,
                  const float* __restrict__ wv, const float* __restrict__ wo,
                  short* __restrict__ xb, short* __restrict__ wqkvb, short* __restrict__ wob)
{
    const size_t t4 = ((size_t)blockIdx.x * 256 + threadIdx.x) * 4;
    const float* src; short* dst; size_t off, doff;
    if (t4 < 4194304)      { src = x;  dst = xb;    off = t4;           doff = t4; }
    else if (t4 < 5242880) { src = wq; dst = wqkvb; off = t4 - 4194304; doff = t4 - 4194304; }
    else if (t4 < 6291456) { src = wk; dst = wqkvb; off = t4 - 5242880; doff = t4 - 4194304; }
    else if (t4 < 7340032) { src = wv; dst = wqkvb; off = t4 - 6291456; doff = t4 - 4194304; }
    else                   { src = wo; dst = wob;   off = t4 - 7340032; doff = t4 - 7340032; }
    float4 v = *(const float4*)(src + off);
    short4v s = { f2bf(v.x), f2bf(v.y), f2bf(v.z), f2bf(v.w) };
    *(short4v*)(dst + doff) = s;
}

// ---------------- bf16 MFMA GEMM NT 128x128, BK=64 XOR-swizzled, 2-phase dbuf ----------------
// Epilogue: which==0/1 -> fused RMSNorm+RoPE -> Qb/Kb bf16 [B,H,S,HD]
//           which==2   -> Vt f16 [B,H,HD,S]
__global__ __launch_bounds__(256)
void gemm_qkv(const short* __restrict__ A, const short* __restrict__ Bw,
              short* __restrict__ Qb, short* __restrict__ Kb, short* __restrict__ Vt,
              const float* __restrict__ q_scale, const float* __restrict__ k_scale,
              const float* __restrict__ rope_cos, const float* __restrict__ rope_sin)
{
    __shared__ __align__(16) short As[2][128*64];   // 2 x 16KB
    __shared__ __align__(16) short Bs[2][128*64];   // 2 x 16KB  (total 64KB)
    const int tid = threadIdx.x;
    const int w = tid >> 6, lane = tid & 63, quad = lane >> 4, l16 = lane & 15;
    const int wr = w >> 1, wc = w & 1;
    const int bm0 = blockIdx.x * 128, bn0 = blockIdx.y * 128;

    // gld16 staging, 4 calls each for A/B. Call j stages slots p=j*256+tid:
    // row = p>>3 (=j*32 + tid>>3), kslot = p&7; slot holds chunk kch = kslot ^ (row&7).
    const int row_ = tid >> 3;
    const int kslot = tid & 7;
    const short* gA[4]; const short* gB[4];
    #pragma unroll
    for (int j = 0; j < 4; ++j) {
        const int row = j*32 + row_;
        const int kch = kslot ^ (row & 7);
        gA[j] = A  + (size_t)(bm0 + row) * 1024 + kch*8;
        gB[j] = Bw + (size_t)(bn0 + row) * 1024 + kch*8;
    }

    f32x4 acc[4][4];
    #pragma unroll
    for (int i = 0; i < 4; ++i)
        #pragma unroll
        for (int j = 0; j < 4; ++j) acc[i][j] = (f32x4){0.f,0.f,0.f,0.f};

    // prologue: stage K-tile 0 into buffer 0, drain, barrier
    #pragma unroll
    for (int j = 0; j < 4; ++j) {
        gld16(gA[j], &As[0][j*2048 + w*512]);
        gld16(gB[j], &Bs[0][j*2048 + w*512]);
    }
    asm volatile("s_waitcnt vmcnt(0)" ::: "memory");
    __builtin_amdgcn_s_barrier();
    __builtin_amdgcn_sched_barrier(0);

    int cur = 0;
    for (int t = 0; t < 16; ++t) {
        // issue next K-tile loads into the other buffer (stay in flight during MFMA)
        if (t < 15) {
            const int k0 = (t + 1) * 64;
            #pragma unroll
            for (int j = 0; j < 4; ++j) {
                gld16(gA[j] + k0, &As[cur ^ 1][j*2048 + w*512]);
                gld16(gB[j] + k0, &Bs[cur ^ 1][j*2048 + w*512]);
            }
        }
        __builtin_amdgcn_sched_barrier(0);

        short8 af[2][4], bfr[2][4];
        #pragma unroll
        for (int ph = 0; ph < 2; ++ph)
            #pragma unroll
            for (int i = 0; i < 4; ++i) {
                const int ra = wr*64 + i*16 + l16;
                af[ph][i]  = *(const short8*)(&As[cur][ra*64 + (((ph*4 + quad) ^ (ra & 7)) << 3)]);
                const int rb = wc*64 + i*16 + l16;
                bfr[ph][i] = *(const short8*)(&Bs[cur][rb*64 + (((ph*4 + quad) ^ (rb & 7)) << 3)]);
            }
        #pragma unroll
        for (int ph = 0; ph < 2; ++ph)
            #pragma unroll
            for (int i = 0; i < 4; ++i)
                #pragma unroll
                for (int j = 0; j < 4; ++j)
                    acc[i][j] = __builtin_amdgcn_mfma_f32_16x16x32_bf16(af[ph][i], bfr[ph][j], acc[i][j], 0, 0, 0);

        // wait own next-tile stores, then barrier: next iter's buffer is ready,
        // and all waves' reads of buf[cur] are done before anyone overwrites it.
        asm volatile("s_waitcnt vmcnt(0)" ::: "memory");
        __builtin_amdgcn_s_barrier();
        __builtin_amdgcn_sched_barrier(0);
        cur ^= 1;
    }

    // wave-uniform: this wave's 64 n-columns = one (which, head) pair
    const int nbase = bn0 + wc*64;
    const int which = nbase >> 10;
    const int h     = (nbase & 1023) >> 6;

    if (which < 2) {
        const float* sc = which ? k_scale : q_scale;
        short* dst      = which ? Kb : Qb;
        const float fold = which ? 1.0f : 0.18033688011112042f;  // q: (1/8)*log2(e)
        float scv[4];
        #pragma unroll
        for (int j = 0; j < 4; ++j) scv[j] = sc[j*16 + l16];
        #pragma unroll
        for (int i = 0; i < 4; ++i) {
            #pragma unroll
            for (int r = 0; r < 4; ++r) {
                const int m = bm0 + wr*64 + i*16 + quad*4 + r;
                const int b = m >> 11, s = m & (S_-1);
                float ss = 0.f;
                #pragma unroll
                for (int j = 0; j < 4; ++j) ss += acc[i][j][r] * acc[i][j][r];
                #pragma unroll
                for (int msk = 1; msk <= 8; msk <<= 1) ss += __shfl_xor(ss, msk, 64);
                const float rn = rsqrtf(ss * (1.0f/64.0f) + 1e-6f);
                #pragma unroll
                for (int j = 0; j < 4; ++j) {
                    const int hd = j*16 + l16;
                    const float nv = acc[i][j][r] * rn * scv[j];
                    const float c  = rope_cos[s*32 + (hd >> 1)];
                    const float sn = rope_sin[s*32 + (hd >> 1)];
                    const float partner = __shfl_xor(nv, 1, 64);
                    const float o = (hd & 1) ? (partner * sn + nv * c) : (nv * c - partner * sn);
                    dst[(((size_t)b*H_ + h)*S_ + s)*HD_ + hd] = f2bf(o * fold);
                }
            }
        }
    } else {
        #pragma unroll
        for (int i = 0; i < 4; ++i)
            #pragma unroll
            for (int r = 0; r < 4; ++r) {
                const int m = bm0 + wr*64 + i*16 + quad*4 + r;
                const int b = m >> 11, s = m & (S_-1);
                #pragma unroll
                for (int j = 0; j < 4; ++j) {
                    const int hd = j*16 + l16;
                    Vt[(((size_t)b*H_ + h)*HD_ + hd)*S_ + s] = f2h(acc[i][j][r]);
                }
            }
    }
}

// ---------------- out-proj GEMM 64x128, combine fused, po register-prefetch ----------------
__global__ __launch_bounds__(256)
void gemm_out(const short* __restrict__ po, const float* __restrict__ pl,
              const short* __restrict__ Bw, float* __restrict__ C)
{
    __shared__ __align__(16) short As[64*32];
    __shared__ __align__(16) short Bs[128*32];
    const int tid = threadIdx.x;
    const int w = tid >> 6, lane = tid & 63, quad = lane >> 4, l16 = lane & 15;
    const int bm0 = blockIdx.x * 64, bn0 = blockIdx.y * 128;

    const int srow = tid >> 2;
    const int skch = (tid & 3) * 8;
    const int m = bm0 + srow;
    const int b = m >> 11, s = m & (S_-1);
    const short* gB0 = Bw + (size_t)(bn0 + srow) * 1024 + skch;
    const short* gB1 = Bw + (size_t)(bn0 + 64 + srow) * 1024 + skch;
    short* lB0 = Bs + w*512;
    short* lB1 = Bs + 2048 + w*512;

    float inv[16];
    #pragma unroll
    for (int h = 0; h < 16; ++h)
        inv[h] = 1.0f / (pl[((size_t)(b*16 + h))*S_ + s] + pl[65536 + ((size_t)(b*16 + h))*S_ + s]);

    f32x4 acc[4][2];
    #pragma unroll
    for (int i = 0; i < 4; ++i) {
        acc[i][0] = (f32x4){0.f,0.f,0.f,0.f};
        acc[i][1] = (f32x4){0.f,0.f,0.f,0.f};
    }

    // prefetch k0=0 po chunks
    half8 c0 = *(const half8*)(po +            (size_t)m*1024 + skch);
    half8 c1 = *(const half8*)(po + 4194304 + (size_t)m*1024 + skch);

    for (int k0 = 0; k0 < 1024; k0 += 32) {
        const int h = k0 >> 6;          // head uniform per iter (skch+7 <= 31)
        short8 a;
        #pragma unroll
        for (int j = 0; j < 8; ++j)
            a[j] = f2bf(((float)c0[j] + (float)c1[j]) * inv[h]);
        __syncthreads();
        *(short8*)(As + srow*32 + skch) = a;
        gld16(gB0 + k0, lB0);
        gld16(gB1 + k0, lB1);
        __syncthreads();
        if (k0 < 1024 - 32) {           // issue next po loads before MFMA block
            c0 = *(const half8*)(po +            (size_t)m*1024 + k0 + 32 + skch);
            c1 = *(const half8*)(po + 4194304 + (size_t)m*1024 + k0 + 32 + skch);
        }
        short8 af[4], bfr[2];
        #pragma unroll
        for (int i = 0; i < 4; ++i)
            af[i] = *(const short8*)(As + (i*16 + l16)*32 + quad*8);
        #pragma unroll
        for (int j = 0; j < 2; ++j)
            bfr[j] = *(const short8*)(Bs + (w*32 + j*16 + l16)*32 + quad*8);
        #pragma unroll
        for (int i = 0; i < 4; ++i)
            #pragma unroll
            for (int j = 0; j < 2; ++j)
                acc[i][j] = __builtin_amdgcn_mfma_f32_16x16x32_bf16(af[i], bfr[j], acc[i][j], 0, 0, 0);
    }

    #pragma unroll
    for (int i = 0; i < 4; ++i)
        #pragma unroll
        for (int r = 0; r < 4; ++r) {
            const int mm = bm0 + i*16 + quad*4 + r;
            #pragma unroll
            for (int j = 0; j < 2; ++j) {
                const int n = bn0 + w*32 + j*16 + l16;
                C[(size_t)mm*1024 + n] = acc[i][j][r];
            }
        }
}

// ---------------- MFMA flash attention partial, split-K=2, XCD-swizzled, setprio ----------------
__global__ __launch_bounds__(256)
void flash_mfma(const short* __restrict__ qb, const short* __restrict__ kb,
                const short* __restrict__ vt, short* __restrict__ po, float* __restrict__ pl)
{
    __shared__ __align__(16) short Ks[64*64];
    __shared__ __align__(16) short Vs[64*64];   // f16 bits, [d][key] swizzled

    const int id   = blockIdx.x;
    const int xcd  = id & 7;
    const int rest = id >> 3;
    const int qblk = rest & 15;               // 16 q-blocks of 128
    const int g    = (rest >> 4) * 8 + xcd;   // (bh,sp) group 0..63
    const int bh   = g >> 1;
    const int sp   = g & 1;

    const int tid  = threadIdx.x;
    const int wv   = tid >> 6;
    const int lane = tid & 63;
    const int quad = lane >> 4;
    const int l16  = lane & 15;
    const int b    = bh >> 4, h = bh & (H_-1);
    const int q0   = qblk * 128 + wv * 32;
    const int kt0  = sp * KSPAN_;
    const size_t hbase = (size_t)bh * S_ * HD_;
    const size_t vbase = (size_t)bh * HD_ * S_;
    short* po_sp = po + (size_t)sp * 4194304;
    float* pl_sp = pl + (size_t)sp * 65536;

    const int c0r = tid >> 3,       c0c = tid & 7;
    const int c1r = (tid+256) >> 3, c1c = (tid+256) & 7;

    short8 qfrag[2][2];
    #pragma unroll
    for (int qf = 0; qf < 2; ++qf)
        #pragma unroll
        for (int c = 0; c < 2; ++c)
            qfrag[qf][c] = *(const short8*)(qb + hbase + (size_t)(q0 + qf*16 + l16)*HD_ + c*32 + quad*8);

    f32x4 Oacc[2][4];
    #pragma unroll
    for (int qf = 0; qf < 2; ++qf)
        #pragma unroll
        for (int dt = 0; dt < 4; ++dt) Oacc[qf][dt] = (f32x4){0.f,0.f,0.f,0.f};
    float l_lane[2] = {0.f, 0.f};

    short8 rk0 = *(const short8*)(kb + hbase + (size_t)(kt0 + c0r)*HD_ + c0c*8);
    short8 rk1 = *(const short8*)(kb + hbase + (size_t)(kt0 + c1r)*HD_ + c1c*8);
    short8 rv0 = *(const short8*)(vt + vbase + (size_t)c0r*S_ + kt0 + c0c*8);
    short8 rv1 = *(const short8*)(vt + vbase + (size_t)c1r*S_ + kt0 + c1c*8);

    #pragma unroll 1
    for (int t = 0; t < KSPAN_/64; ++t) {
        __syncthreads();
        *(short8*)(Ks + c0r*64 + ((c0c ^ (c0r & 7)) << 3)) = rk0;
        *(short8*)(Ks + c1r*64 + ((c1c ^ (c1r & 7)) << 3)) = rk1;
        *(short8*)(Vs + c0r*64 + ((c0c ^ (c0r & 7)) << 3)) = rv0;
        *(short8*)(Vs + c1r*64 + ((c1c ^ (c1r & 7)) << 3)) = rv1;
        __syncthreads();
        if (t < KSPAN_/64 - 1) {
            const int ktn = kt0 + (t+1)*64;
            rk0 = *(const short8*)(kb + hbase + (size_t)(ktn + c0r)*HD_ + c0c*8);
            rk1 = *(const short8*)(kb + hbase + (size_t)(ktn + c1r)*HD_ + c1c*8);
            rv0 = *(const short8*)(vt + vbase + (size_t)c0r*S_ + ktn + c0c*8);
            rv1 = *(const short8*)(vt + vbase + (size_t)c1r*S_ + ktn + c1c*8);
        }

        #pragma unroll
        for (int st = 0; st < 4; ++st) {
            short8 kf0 = *(const short8*)(Ks + (st*16 + l16)*64 + (((quad    ) ^ (l16 & 7)) << 3));
            short8 kf1 = *(const short8*)(Ks + (st*16 + l16)*64 + (((4 + quad) ^ (l16 & 7)) << 3));
            const int ch16 = st*2 + (quad >> 1);
            const int sw   = ((ch16 ^ (l16 & 7)) << 3) + (quad & 1)*4;
            half4 va[4];
            #pragma unroll
            for (int dt = 0; dt < 4; ++dt)
                va[dt] = *(const half4*)(Vs + (dt*16 + l16)*64 + sw);
            #pragma unroll
            for (int qf = 0; qf < 2; ++qf) {
                f32x4 acc = (f32x4){0.f,0.f,0.f,0.f};
                __builtin_amdgcn_s_setprio(1);
                acc = __builtin_amdgcn_mfma_f32_16x16x32_bf16(kf0, qfrag[qf][0], acc, 0, 0, 0);
                acc = __builtin_amdgcn_mfma_f32_16x16x32_bf16(kf1, qfrag[qf][1], acc, 0, 0, 0);
                __builtin_amdgcn_s_setprio(0);
                half4 pb;
                #pragma unroll
                for (int r = 0; r < 4; ++r) {
                    float p = __builtin_amdgcn_exp2f(acc[r] - 12.0f);
                    l_lane[qf] += p;
                    pb[r] = (_Float16)p;
                }
                __builtin_amdgcn_s_setprio(1);
                #pragma unroll
                for (int dt = 0; dt < 4; ++dt)
                    Oacc[qf][dt] = __builtin_amdgcn_mfma_f32_16x16x16f16(va[dt], pb, Oacc[qf][dt], 0, 0, 0);
                __builtin_amdgcn_s_setprio(0);
            }
        }
    }

    #pragma unroll
    for (int qf = 0; qf < 2; ++qf) {
        l_lane[qf] += __shfl_xor(l_lane[qf], 16, 64);
        l_lane[qf] += __shfl_xor(l_lane[qf], 32, 64);
        if (quad == 0) pl_sp[(size_t)bh*S_ + q0 + qf*16 + l16] = l_lane[qf];
    }
    #pragma unroll
    for (int qf = 0; qf < 2; ++qf) {
        const int s = q0 + qf*16 + l16;
        #pragma unroll
        for (int dt = 0; dt < 4; ++dt) {
            short4v o;
            #pragma unroll
            for (int r = 0; r < 4; ++r) o[r] = f2h(Oacc[qf][dt][r]);
            *(short4v*)(po_sp + (((size_t)b*S_ + s)*H_ + h)*HD_ + dt*16 + quad*4) = o;
        }
    }
}

extern "C" void kernel_launch(void* const* d_in, const int* in_sizes, int n_in,
                              void* d_out, int out_size, void* d_ws, size_t ws_size,
                              hipStream_t stream)
{
    (void)in_sizes; (void)n_in; (void)out_size; (void)ws_size;
    const float* x        = (const float*)d_in[0];
    const float* wq       = (const float*)d_in[1];
    const float* wk       = (const float*)d_in[2];
    const float* wv       = (const float*)d_in[3];
    const float* wo       = (const float*)d_in[4];
    const float* q_scale  = (const float*)d_in[5];
    const float* k_scale  = (const float*)d_in[6];
    const float* rope_cos = (const float*)d_in[7];
    const float* rope_sin = (const float*)d_in[8];
    float* out = (float*)d_out;
    short* ws  = (short*)d_ws;

    short* qbh   = ws;                 // 4M shorts
    short* kbh   = ws + 4194304;
    short* vt    = ws + 8388608;
    short* xb    = ws + 16777216;
    short* wqkvb = ws + 20971520;      // 3M shorts
    short* wob   = ws + 24117248;      // 1M shorts
    short* po    = ws + 25165824;      // 2 x 4M shorts (f16)
    float* pl    = (float*)(ws + 33554432);  // 2 x 64K floats

    convert_bf16<<<dim3(8192), 256, 0, stream>>>(x, wq, wk, wv, wo, xb, wqkvb, wob);
    gemm_qkv<<<dim3(M_/128, 24), 256, 0, stream>>>(xb, wqkvb, qbh, kbh, vt,
                                                   q_scale, k_scale, rope_cos, rope_sin);
    flash_mfma<<<dim3((S_/128)*B_*H_*SPLIT_), 256, 0, stream>>>(qbh, kbh, vt, po, pl);
    gemm_out<<<dim3(M_/64, D_/128), 256, 0, stream>>>(po, pl, wob, out);
}

// Round 5
// 212.674 us; speedup vs baseline: 1.5805x; 1.0096x over previous
//
#include <hip/hip_runtime.h>
#include <hip/hip_bf16.h>

// RoPEAttention B=2 S=2048 D=1024 H=16 HD=64, fp32 in/out.
// R14: flash PV step -> mfma_f32_16x16x32_f16 (K=32), halving PV inst count
//      (4.19M -> 2.1M). Key insight: MFMA sums over architectural k-slots, so a
//      permutation applied to BOTH A (V^T) and B (P) operands is identity-
//      preserving. kappa(quad*8+j) = quad*4+(j&3)+16*(j>>2) makes each lane's
//      8 B-slots exactly the 8 p-values it owns from two QK 16-blocks (no
//      shuffles); A-operand = the two half4 V^T reads packed into one half8.
//      Also reverts R13 setprio (measured -6% on this kernel: lockstep waves).
// R11: gemm_qkv 2-phase dbuf pipeline (kept).
// ws (shorts): qbh[0,4M) kbh[4M,8M) vt[8M,12M) xb[16M,20M)
//              wqkvb[20M,23M) wob[23M,24M) po[24M,32M) pl(fp32) after.

#define B_ 2
#define S_ 2048
#define D_ 1024
#define H_ 16
#define HD_ 64
#define M_ (B_*S_)
#define SPLIT_ 2
#define KSPAN_ (S_/SPLIT_)    // 1024 keys per split

typedef __attribute__((ext_vector_type(8))) short short8;
typedef __attribute__((ext_vector_type(4))) short short4v;
typedef __attribute__((ext_vector_type(4))) float f32x4;
typedef __attribute__((ext_vector_type(4))) _Float16 half4;
typedef __attribute__((ext_vector_type(8))) _Float16 half8;

static __device__ __forceinline__ short f2bf(float f) {
    __hip_bfloat16 h = __float2bfloat16(f);
    return *reinterpret_cast<short*>(&h);
}
static __device__ __forceinline__ short f2h(float f) {
    _Float16 h = (_Float16)f;
    return *reinterpret_cast<short*>(&h);
}

typedef __attribute__((address_space(1))) const unsigned int gu32_t;
typedef __attribute__((address_space(3))) unsigned int lu32_t;
static __device__ __forceinline__ void gld16(const short* g, short* l) {
    __builtin_amdgcn_global_load_lds((gu32_t*)g, (lu32_t*)l, 16, 0, 0);
}

// ---------------- fp32 -> bf16 convert: x, wq|wk|wv (concat), wo ----------------
__global__ __launch_bounds__(256)
void convert_bf16(const float* __restrict__ x,
                  const float* __restrict__ wq, const float* __restrict__ wk,
                  const float* __restrict__ wv, const float* __restrict__ wo,
                  short* __restrict__ xb, short* __restrict__ wqkvb, short* __restrict__ wob)
{
    const size_t t4 = ((size_t)blockIdx.x * 256 + threadIdx.x) * 4;
    const float* src; short* dst; size_t off, doff;
    if (t4 < 4194304)      { src = x;  dst = xb;    off = t4;           doff = t4; }
    else if (t4 < 5242880) { src = wq; dst = wqkvb; off = t4 - 4194304; doff = t4 - 4194304; }
    else if (t4 < 6291456) { src = wk; dst = wqkvb; off = t4 - 5242880; doff = t4 - 4194304; }
    else if (t4 < 7340032) { src = wv; dst = wqkvb; off = t4 - 6291456; doff = t4 - 4194304; }
    else                   { src = wo; dst = wob;   off = t4 - 7340032; doff = t4 - 7340032; }
    float4 v = *(const float4*)(src + off);
    short4v s = { f2bf(v.x), f2bf(v.y), f2bf(v.z), f2bf(v.w) };
    *(short4v*)(dst + doff) = s;
}

// ---------------- bf16 MFMA GEMM NT 128x128, BK=64 XOR-swizzled, 2-phase dbuf ----------------
// Epilogue: which==0/1 -> fused RMSNorm+RoPE -> Qb/Kb bf16 [B,H,S,HD]
//           which==2   -> Vt f16 [B,H,HD,S]
__global__ __launch_bounds__(256)
void gemm_qkv(const short* __restrict__ A, const short* __restrict__ Bw,
              short* __restrict__ Qb, short* __restrict__ Kb, short* __restrict__ Vt,
              const float* __restrict__ q_scale, const float* __restrict__ k_scale,
              const float* __restrict__ rope_cos, const float* __restrict__ rope_sin)
{
    __shared__ __align__(16) short As[2][128*64];   // 2 x 16KB
    __shared__ __align__(16) short Bs[2][128*64];   // 2 x 16KB  (total 64KB)
    const int tid = threadIdx.x;
    const int w = tid >> 6, lane = tid & 63, quad = lane >> 4, l16 = lane & 15;
    const int wr = w >> 1, wc = w & 1;
    const int bm0 = blockIdx.x * 128, bn0 = blockIdx.y * 128;

    // gld16 staging, 4 calls each for A/B. Call j stages slots p=j*256+tid:
    // row = p>>3 (=j*32 + tid>>3), kslot = p&7; slot holds chunk kch = kslot ^ (row&7).
    const int row_ = tid >> 3;
    const int kslot = tid & 7;
    const short* gA[4]; const short* gB[4];
    #pragma unroll
    for (int j = 0; j < 4; ++j) {
        const int row = j*32 + row_;
        const int kch = kslot ^ (row & 7);
        gA[j] = A  + (size_t)(bm0 + row) * 1024 + kch*8;
        gB[j] = Bw + (size_t)(bn0 + row) * 1024 + kch*8;
    }

    f32x4 acc[4][4];
    #pragma unroll
    for (int i = 0; i < 4; ++i)
        #pragma unroll
        for (int j = 0; j < 4; ++j) acc[i][j] = (f32x4){0.f,0.f,0.f,0.f};

    // prologue: stage K-tile 0 into buffer 0, drain, barrier
    #pragma unroll
    for (int j = 0; j < 4; ++j) {
        gld16(gA[j], &As[0][j*2048 + w*512]);
        gld16(gB[j], &Bs[0][j*2048 + w*512]);
    }
    asm volatile("s_waitcnt vmcnt(0)" ::: "memory");
    __builtin_amdgcn_s_barrier();
    __builtin_amdgcn_sched_barrier(0);

    int cur = 0;
    for (int t = 0; t < 16; ++t) {
        // issue next K-tile loads into the other buffer (stay in flight during MFMA)
        if (t < 15) {
            const int k0 = (t + 1) * 64;
            #pragma unroll
            for (int j = 0; j < 4; ++j) {
                gld16(gA[j] + k0, &As[cur ^ 1][j*2048 + w*512]);
                gld16(gB[j] + k0, &Bs[cur ^ 1][j*2048 + w*512]);
            }
        }
        __builtin_amdgcn_sched_barrier(0);

        short8 af[2][4], bfr[2][4];
        #pragma unroll
        for (int ph = 0; ph < 2; ++ph)
            #pragma unroll
            for (int i = 0; i < 4; ++i) {
                const int ra = wr*64 + i*16 + l16;
                af[ph][i]  = *(const short8*)(&As[cur][ra*64 + (((ph*4 + quad) ^ (ra & 7)) << 3)]);
                const int rb = wc*64 + i*16 + l16;
                bfr[ph][i] = *(const short8*)(&Bs[cur][rb*64 + (((ph*4 + quad) ^ (rb & 7)) << 3)]);
            }
        #pragma unroll
        for (int ph = 0; ph < 2; ++ph)
            #pragma unroll
            for (int i = 0; i < 4; ++i)
                #pragma unroll
                for (int j = 0; j < 4; ++j)
                    acc[i][j] = __builtin_amdgcn_mfma_f32_16x16x32_bf16(af[ph][i], bfr[ph][j], acc[i][j], 0, 0, 0);

        // wait own next-tile stores, then barrier: next iter's buffer is ready,
        // and all waves' reads of buf[cur] are done before anyone overwrites it.
        asm volatile("s_waitcnt vmcnt(0)" ::: "memory");
        __builtin_amdgcn_s_barrier();
        __builtin_amdgcn_sched_barrier(0);
        cur ^= 1;
    }

    // wave-uniform: this wave's 64 n-columns = one (which, head) pair
    const int nbase = bn0 + wc*64;
    const int which = nbase >> 10;
    const int h     = (nbase & 1023) >> 6;

    if (which < 2) {
        const float* sc = which ? k_scale : q_scale;
        short* dst      = which ? Kb : Qb;
        const float fold = which ? 1.0f : 0.18033688011112042f;  // q: (1/8)*log2(e)
        float scv[4];
        #pragma unroll
        for (int j = 0; j < 4; ++j) scv[j] = sc[j*16 + l16];
        #pragma unroll
        for (int i = 0; i < 4; ++i) {
            #pragma unroll
            for (int r = 0; r < 4; ++r) {
                const int m = bm0 + wr*64 + i*16 + quad*4 + r;
                const int b = m >> 11, s = m & (S_-1);
                float ss = 0.f;
                #pragma unroll
                for (int j = 0; j < 4; ++j) ss += acc[i][j][r] * acc[i][j][r];
                #pragma unroll
                for (int msk = 1; msk <= 8; msk <<= 1) ss += __shfl_xor(ss, msk, 64);
                const float rn = rsqrtf(ss * (1.0f/64.0f) + 1e-6f);
                #pragma unroll
                for (int j = 0; j < 4; ++j) {
                    const int hd = j*16 + l16;
                    const float nv = acc[i][j][r] * rn * scv[j];
                    const float c  = rope_cos[s*32 + (hd >> 1)];
                    const float sn = rope_sin[s*32 + (hd >> 1)];
                    const float partner = __shfl_xor(nv, 1, 64);
                    const float o = (hd & 1) ? (partner * sn + nv * c) : (nv * c - partner * sn);
                    dst[(((size_t)b*H_ + h)*S_ + s)*HD_ + hd] = f2bf(o * fold);
                }
            }
        }
    } else {
        #pragma unroll
        for (int i = 0; i < 4; ++i)
            #pragma unroll
            for (int r = 0; r < 4; ++r) {
                const int m = bm0 + wr*64 + i*16 + quad*4 + r;
                const int b = m >> 11, s = m & (S_-1);
                #pragma unroll
                for (int j = 0; j < 4; ++j) {
                    const int hd = j*16 + l16;
                    Vt[(((size_t)b*H_ + h)*HD_ + hd)*S_ + s] = f2h(acc[i][j][r]);
                }
            }
    }
}

// ---------------- out-proj GEMM 64x128, combine fused, po register-prefetch ----------------
__global__ __launch_bounds__(256)
void gemm_out(const short* __restrict__ po, const float* __restrict__ pl,
              const short* __restrict__ Bw, float* __restrict__ C)
{
    __shared__ __align__(16) short As[64*32];
    __shared__ __align__(16) short Bs[128*32];
    const int tid = threadIdx.x;
    const int w = tid >> 6, lane = tid & 63, quad = lane >> 4, l16 = lane & 15;
    const int bm0 = blockIdx.x * 64, bn0 = blockIdx.y * 128;

    const int srow = tid >> 2;
    const int skch = (tid & 3) * 8;
    const int m = bm0 + srow;
    const int b = m >> 11, s = m & (S_-1);
    const short* gB0 = Bw + (size_t)(bn0 + srow) * 1024 + skch;
    const short* gB1 = Bw + (size_t)(bn0 + 64 + srow) * 1024 + skch;
    short* lB0 = Bs + w*512;
    short* lB1 = Bs + 2048 + w*512;

    float inv[16];
    #pragma unroll
    for (int h = 0; h < 16; ++h)
        inv[h] = 1.0f / (pl[((size_t)(b*16 + h))*S_ + s] + pl[65536 + ((size_t)(b*16 + h))*S_ + s]);

    f32x4 acc[4][2];
    #pragma unroll
    for (int i = 0; i < 4; ++i) {
        acc[i][0] = (f32x4){0.f,0.f,0.f,0.f};
        acc[i][1] = (f32x4){0.f,0.f,0.f,0.f};
    }

    // prefetch k0=0 po chunks
    half8 c0 = *(const half8*)(po +            (size_t)m*1024 + skch);
    half8 c1 = *(const half8*)(po + 4194304 + (size_t)m*1024 + skch);

    for (int k0 = 0; k0 < 1024; k0 += 32) {
        const int h = k0 >> 6;          // head uniform per iter (skch+7 <= 31)
        short8 a;
        #pragma unroll
        for (int j = 0; j < 8; ++j)
            a[j] = f2bf(((float)c0[j] + (float)c1[j]) * inv[h]);
        __syncthreads();
        *(short8*)(As + srow*32 + skch) = a;
        gld16(gB0 + k0, lB0);
        gld16(gB1 + k0, lB1);
        __syncthreads();
        if (k0 < 1024 - 32) {           // issue next po loads before MFMA block
            c0 = *(const half8*)(po +            (size_t)m*1024 + k0 + 32 + skch);
            c1 = *(const half8*)(po + 4194304 + (size_t)m*1024 + k0 + 32 + skch);
        }
        short8 af[4], bfr[2];
        #pragma unroll
        for (int i = 0; i < 4; ++i)
            af[i] = *(const short8*)(As + (i*16 + l16)*32 + quad*8);
        #pragma unroll
        for (int j = 0; j < 2; ++j)
            bfr[j] = *(const short8*)(Bs + (w*32 + j*16 + l16)*32 + quad*8);
        #pragma unroll
        for (int i = 0; i < 4; ++i)
            #pragma unroll
            for (int j = 0; j < 2; ++j)
                acc[i][j] = __builtin_amdgcn_mfma_f32_16x16x32_bf16(af[i], bfr[j], acc[i][j], 0, 0, 0);
    }

    #pragma unroll
    for (int i = 0; i < 4; ++i)
        #pragma unroll
        for (int r = 0; r < 4; ++r) {
            const int mm = bm0 + i*16 + quad*4 + r;
            #pragma unroll
            for (int j = 0; j < 2; ++j) {
                const int n = bn0 + w*32 + j*16 + l16;
                C[(size_t)mm*1024 + n] = acc[i][j][r];
            }
        }
}

// ---------------- MFMA flash attention partial, split-K=2, XCD-swizzled, PV K=32 ----------------
__global__ __launch_bounds__(256)
void flash_mfma(const short* __restrict__ qb, const short* __restrict__ kb,
                const short* __restrict__ vt, short* __restrict__ po, float* __restrict__ pl)
{
    __shared__ __align__(16) short Ks[64*64];
    __shared__ __align__(16) short Vs[64*64];   // f16 bits, [d][key] swizzled

    const int id   = blockIdx.x;
    const int xcd  = id & 7;
    const int rest = id >> 3;
    const int qblk = rest & 15;               // 16 q-blocks of 128
    const int g    = (rest >> 4) * 8 + xcd;   // (bh,sp) group 0..63
    const int bh   = g >> 1;
    const int sp   = g & 1;

    const int tid  = threadIdx.x;
    const int wv   = tid >> 6;
    const int lane = tid & 63;
    const int quad = lane >> 4;
    const int l16  = lane & 15;
    const int b    = bh >> 4, h = bh & (H_-1);
    const int q0   = qblk * 128 + wv * 32;
    const int kt0  = sp * KSPAN_;
    const size_t hbase = (size_t)bh * S_ * HD_;
    const size_t vbase = (size_t)bh * HD_ * S_;
    short* po_sp = po + (size_t)sp * 4194304;
    float* pl_sp = pl + (size_t)sp * 65536;

    const int c0r = tid >> 3,       c0c = tid & 7;
    const int c1r = (tid+256) >> 3, c1c = (tid+256) & 7;

    short8 qfrag[2][2];
    #pragma unroll
    for (int qf = 0; qf < 2; ++qf)
        #pragma unroll
        for (int c = 0; c < 2; ++c)
            qfrag[qf][c] = *(const short8*)(qb + hbase + (size_t)(q0 + qf*16 + l16)*HD_ + c*32 + quad*8);

    f32x4 Oacc[2][4];
    #pragma unroll
    for (int qf = 0; qf < 2; ++qf)
        #pragma unroll
        for (int dt = 0; dt < 4; ++dt) Oacc[qf][dt] = (f32x4){0.f,0.f,0.f,0.f};
    float l_lane[2] = {0.f, 0.f};

    short8 rk0 = *(const short8*)(kb + hbase + (size_t)(kt0 + c0r)*HD_ + c0c*8);
    short8 rk1 = *(const short8*)(kb + hbase + (size_t)(kt0 + c1r)*HD_ + c1c*8);
    short8 rv0 = *(const short8*)(vt + vbase + (size_t)c0r*S_ + kt0 + c0c*8);
    short8 rv1 = *(const short8*)(vt + vbase + (size_t)c1r*S_ + kt0 + c1c*8);

    #pragma unroll 1
    for (int t = 0; t < KSPAN_/64; ++t) {
        __syncthreads();
        *(short8*)(Ks + c0r*64 + ((c0c ^ (c0r & 7)) << 3)) = rk0;
        *(short8*)(Ks + c1r*64 + ((c1c ^ (c1r & 7)) << 3)) = rk1;
        *(short8*)(Vs + c0r*64 + ((c0c ^ (c0r & 7)) << 3)) = rv0;
        *(short8*)(Vs + c1r*64 + ((c1c ^ (c1r & 7)) << 3)) = rv1;
        __syncthreads();
        if (t < KSPAN_/64 - 1) {
            const int ktn = kt0 + (t+1)*64;
            rk0 = *(const short8*)(kb + hbase + (size_t)(ktn + c0r)*HD_ + c0c*8);
            rk1 = *(const short8*)(kb + hbase + (size_t)(ktn + c1r)*HD_ + c1c*8);
            rv0 = *(const short8*)(vt + vbase + (size_t)c0r*S_ + ktn + c0c*8);
            rv1 = *(const short8*)(vt + vbase + (size_t)c1r*S_ + ktn + c1c*8);
        }

        // Two 32-key chunks per tile; each chunk: 4 QK mfma (2x16-key blocks)
        // + 4 PV mfma at K=32 with permuted k-slots (kappa applied to A and B).
        #pragma unroll
        for (int stp = 0; stp < 2; ++stp) {
            const int st0 = stp*2, st1 = st0 + 1;
            short8 kf00 = *(const short8*)(Ks + (st0*16 + l16)*64 + (((quad    ) ^ (l16 & 7)) << 3));
            short8 kf01 = *(const short8*)(Ks + (st0*16 + l16)*64 + (((4 + quad) ^ (l16 & 7)) << 3));
            short8 kf10 = *(const short8*)(Ks + (st1*16 + l16)*64 + (((quad    ) ^ (l16 & 7)) << 3));
            short8 kf11 = *(const short8*)(Ks + (st1*16 + l16)*64 + (((4 + quad) ^ (l16 & 7)) << 3));
            const int cha = stp*4 + (quad >> 1);
            const int chb = cha + 2;
            const int swa = ((cha ^ (l16 & 7)) << 3) + (quad & 1)*4;
            const int swb = ((chb ^ (l16 & 7)) << 3) + (quad & 1)*4;
            half8 va8[4];
            #pragma unroll
            for (int dt = 0; dt < 4; ++dt) {
                half4 a = *(const half4*)(Vs + (dt*16 + l16)*64 + swa);
                half4 c = *(const half4*)(Vs + (dt*16 + l16)*64 + swb);
                va8[dt] = __builtin_shufflevector(a, c, 0, 1, 2, 3, 4, 5, 6, 7);
            }
            #pragma unroll
            for (int qf = 0; qf < 2; ++qf) {
                f32x4 sa = (f32x4){0.f,0.f,0.f,0.f};
                f32x4 sb = (f32x4){0.f,0.f,0.f,0.f};
                sa = __builtin_amdgcn_mfma_f32_16x16x32_bf16(kf00, qfrag[qf][0], sa, 0, 0, 0);
                sa = __builtin_amdgcn_mfma_f32_16x16x32_bf16(kf01, qfrag[qf][1], sa, 0, 0, 0);
                sb = __builtin_amdgcn_mfma_f32_16x16x32_bf16(kf10, qfrag[qf][0], sb, 0, 0, 0);
                sb = __builtin_amdgcn_mfma_f32_16x16x32_bf16(kf11, qfrag[qf][1], sb, 0, 0, 0);
                half8 pb8;
                #pragma unroll
                for (int r = 0; r < 4; ++r) {
                    float pa = __builtin_amdgcn_exp2f(sa[r] - 12.0f);
                    float pc = __builtin_amdgcn_exp2f(sb[r] - 12.0f);
                    l_lane[qf] += pa + pc;
                    pb8[r]     = (_Float16)pa;
                    pb8[4 + r] = (_Float16)pc;
                }
                #pragma unroll
                for (int dt = 0; dt < 4; ++dt)
                    Oacc[qf][dt] = __builtin_amdgcn_mfma_f32_16x16x32_f16(va8[dt], pb8, Oacc[qf][dt], 0, 0, 0);
            }
        }
    }

    #pragma unroll
    for (int qf = 0; qf < 2; ++qf) {
        l_lane[qf] += __shfl_xor(l_lane[qf], 16, 64);
        l_lane[qf] += __shfl_xor(l_lane[qf], 32, 64);
        if (quad == 0) pl_sp[(size_t)bh*S_ + q0 + qf*16 + l16] = l_lane[qf];
    }
    #pragma unroll
    for (int qf = 0; qf < 2; ++qf) {
        const int s = q0 + qf*16 + l16;
        #pragma unroll
        for (int dt = 0; dt < 4; ++dt) {
            short4v o;
            #pragma unroll
            for (int r = 0; r < 4; ++r) o[r] = f2h(Oacc[qf][dt][r]);
            *(short4v*)(po_sp + (((size_t)b*S_ + s)*H_ + h)*HD_ + dt*16 + quad*4) = o;
        }
    }
}

extern "C" void kernel_launch(void* const* d_in, const int* in_sizes, int n_in,
                              void* d_out, int out_size, void* d_ws, size_t ws_size,
                              hipStream_t stream)
{
    (void)in_sizes; (void)n_in; (void)out_size; (void)ws_size;
    const float* x        = (const float*)d_in[0];
    const float* wq       = (const float*)d_in[1];
    const float* wk       = (const float*)d_in[2];
    const float* wv       = (const float*)d_in[3];
    const float* wo       = (const float*)d_in[4];
    const float* q_scale  = (const float*)d_in[5];
    const float* k_scale  = (const float*)d_in[6];
    const float* rope_cos = (const float*)d_in[7];
    const float* rope_sin = (const float*)d_in[8];
    float* out = (float*)d_out;
    short* ws  = (short*)d_ws;

    short* qbh   = ws;                 // 4M shorts
    short* kbh   = ws + 4194304;
    short* vt    = ws + 8388608;
    short* xb    = ws + 16777216;
    short* wqkvb = ws + 20971520;      // 3M shorts
    short* wob   = ws + 24117248;      // 1M shorts
    short* po    = ws + 25165824;      // 2 x 4M shorts (f16)
    float* pl    = (float*)(ws + 33554432);  // 2 x 64K floats

    convert_bf16<<<dim3(8192), 256, 0, stream>>>(x, wq, wk, wv, wo, xb, wqkvb, wob);
    gemm_qkv<<<dim3(M_/128, 24), 256, 0, stream>>>(xb, wqkvb, qbh, kbh, vt,
                                                   q_scale, k_scale, rope_cos, rope_sin);
    flash_mfma<<<dim3((S_/128)*B_*H_*SPLIT_), 256, 0, stream>>>(qbh, kbh, vt, po, pl);
    gemm_out<<<dim3(M_/64, D_/128), 256, 0, stream>>>(po, pl, wob, out);
}

// Round 6
// 207.463 us; speedup vs baseline: 1.6202x; 1.0251x over previous
//
#include <hip/hip_runtime.h>
#include <hip/hip_bf16.h>

// RoPEAttention B=2 S=2048 D=1024 H=16 HD=64, fp32 in/out.
// R15: (a) flash reverted to R2-exact (measured 56.0us best; R14 PV-K=32 was
//      58.7 -> flash is NOT mfma-issue-bound; R13 setprio was -6%).
//      (b) gemm_out -> R11-style 2-phase pipeline: BK=64, double-buffered LDS
//      (XOR-swizzled, same scheme as gemm_qkv), ONE raw s_barrier per K-iter
//      (was 2 syncthreads x 32 iters), po->reg prefetch + gld16 B prefetch
//      issued before the MFMA phase. Head index = iter index (static unroll).
// R11: gemm_qkv 2-phase dbuf pipeline (kept).
// ws (shorts): qbh[0,4M) kbh[4M,8M) vt[8M,12M) xb[16M,20M)
//              wqkvb[20M,23M) wob[23M,24M) po[24M,32M) pl(fp32) after.

#define B_ 2
#define S_ 2048
#define D_ 1024
#define H_ 16
#define HD_ 64
#define M_ (B_*S_)
#define SPLIT_ 2
#define KSPAN_ (S_/SPLIT_)    // 1024 keys per split

typedef __attribute__((ext_vector_type(8))) short short8;
typedef __attribute__((ext_vector_type(4))) short short4v;
typedef __attribute__((ext_vector_type(4))) float f32x4;
typedef __attribute__((ext_vector_type(4))) _Float16 half4;
typedef __attribute__((ext_vector_type(8))) _Float16 half8;

static __device__ __forceinline__ short f2bf(float f) {
    __hip_bfloat16 h = __float2bfloat16(f);
    return *reinterpret_cast<short*>(&h);
}
static __device__ __forceinline__ short f2h(float f) {
    _Float16 h = (_Float16)f;
    return *reinterpret_cast<short*>(&h);
}

typedef __attribute__((address_space(1))) const unsigned int gu32_t;
typedef __attribute__((address_space(3))) unsigned int lu32_t;
static __device__ __forceinline__ void gld16(const short* g, short* l) {
    __builtin_amdgcn_global_load_lds((gu32_t*)g, (lu32_t*)l, 16, 0, 0);
}

// ---------------- fp32 -> bf16 convert: x, wq|wk|wv (concat), wo ----------------
__global__ __launch_bounds__(256)
void convert_bf16(const float* __restrict__ x,
                  const float* __restrict__ wq, const float* __restrict__ wk,
                  const float* __restrict__ wv, const float* __restrict__ wo,
                  short* __restrict__ xb, short* __restrict__ wqkvb, short* __restrict__ wob)
{
    const size_t t4 = ((size_t)blockIdx.x * 256 + threadIdx.x) * 4;
    const float* src; short* dst; size_t off, doff;
    if (t4 < 4194304)      { src = x;  dst = xb;    off = t4;           doff = t4; }
    else if (t4 < 5242880) { src = wq; dst = wqkvb; off = t4 - 4194304; doff = t4 - 4194304; }
    else if (t4 < 6291456) { src = wk; dst = wqkvb; off = t4 - 5242880; doff = t4 - 4194304; }
    else if (t4 < 7340032) { src = wv; dst = wqkvb; off = t4 - 6291456; doff = t4 - 4194304; }
    else                   { src = wo; dst = wob;   off = t4 - 7340032; doff = t4 - 7340032; }
    float4 v = *(const float4*)(src + off);
    short4v s = { f2bf(v.x), f2bf(v.y), f2bf(v.z), f2bf(v.w) };
    *(short4v*)(dst + doff) = s;
}

// ---------------- bf16 MFMA GEMM NT 128x128, BK=64 XOR-swizzled, 2-phase dbuf ----------------
// Epilogue: which==0/1 -> fused RMSNorm+RoPE -> Qb/Kb bf16 [B,H,S,HD]
//           which==2   -> Vt f16 [B,H,HD,S]
__global__ __launch_bounds__(256)
void gemm_qkv(const short* __restrict__ A, const short* __restrict__ Bw,
              short* __restrict__ Qb, short* __restrict__ Kb, short* __restrict__ Vt,
              const float* __restrict__ q_scale, const float* __restrict__ k_scale,
              const float* __restrict__ rope_cos, const float* __restrict__ rope_sin)
{
    __shared__ __align__(16) short As[2][128*64];   // 2 x 16KB
    __shared__ __align__(16) short Bs[2][128*64];   // 2 x 16KB  (total 64KB)
    const int tid = threadIdx.x;
    const int w = tid >> 6, lane = tid & 63, quad = lane >> 4, l16 = lane & 15;
    const int wr = w >> 1, wc = w & 1;
    const int bm0 = blockIdx.x * 128, bn0 = blockIdx.y * 128;

    const int row_ = tid >> 3;
    const int kslot = tid & 7;
    const short* gA[4]; const short* gB[4];
    #pragma unroll
    for (int j = 0; j < 4; ++j) {
        const int row = j*32 + row_;
        const int kch = kslot ^ (row & 7);
        gA[j] = A  + (size_t)(bm0 + row) * 1024 + kch*8;
        gB[j] = Bw + (size_t)(bn0 + row) * 1024 + kch*8;
    }

    f32x4 acc[4][4];
    #pragma unroll
    for (int i = 0; i < 4; ++i)
        #pragma unroll
        for (int j = 0; j < 4; ++j) acc[i][j] = (f32x4){0.f,0.f,0.f,0.f};

    // prologue: stage K-tile 0 into buffer 0, drain, barrier
    #pragma unroll
    for (int j = 0; j < 4; ++j) {
        gld16(gA[j], &As[0][j*2048 + w*512]);
        gld16(gB[j], &Bs[0][j*2048 + w*512]);
    }
    asm volatile("s_waitcnt vmcnt(0)" ::: "memory");
    __builtin_amdgcn_s_barrier();
    __builtin_amdgcn_sched_barrier(0);

    int cur = 0;
    for (int t = 0; t < 16; ++t) {
        if (t < 15) {
            const int k0 = (t + 1) * 64;
            #pragma unroll
            for (int j = 0; j < 4; ++j) {
                gld16(gA[j] + k0, &As[cur ^ 1][j*2048 + w*512]);
                gld16(gB[j] + k0, &Bs[cur ^ 1][j*2048 + w*512]);
            }
        }
        __builtin_amdgcn_sched_barrier(0);

        short8 af[2][4], bfr[2][4];
        #pragma unroll
        for (int ph = 0; ph < 2; ++ph)
            #pragma unroll
            for (int i = 0; i < 4; ++i) {
                const int ra = wr*64 + i*16 + l16;
                af[ph][i]  = *(const short8*)(&As[cur][ra*64 + (((ph*4 + quad) ^ (ra & 7)) << 3)]);
                const int rb = wc*64 + i*16 + l16;
                bfr[ph][i] = *(const short8*)(&Bs[cur][rb*64 + (((ph*4 + quad) ^ (rb & 7)) << 3)]);
            }
        #pragma unroll
        for (int ph = 0; ph < 2; ++ph)
            #pragma unroll
            for (int i = 0; i < 4; ++i)
                #pragma unroll
                for (int j = 0; j < 4; ++j)
                    acc[i][j] = __builtin_amdgcn_mfma_f32_16x16x32_bf16(af[ph][i], bfr[ph][j], acc[i][j], 0, 0, 0);

        asm volatile("s_waitcnt vmcnt(0)" ::: "memory");
        __builtin_amdgcn_s_barrier();
        __builtin_amdgcn_sched_barrier(0);
        cur ^= 1;
    }

    const int nbase = bn0 + wc*64;
    const int which = nbase >> 10;
    const int h     = (nbase & 1023) >> 6;

    if (which < 2) {
        const float* sc = which ? k_scale : q_scale;
        short* dst      = which ? Kb : Qb;
        const float fold = which ? 1.0f : 0.18033688011112042f;  // q: (1/8)*log2(e)
        float scv[4];
        #pragma unroll
        for (int j = 0; j < 4; ++j) scv[j] = sc[j*16 + l16];
        #pragma unroll
        for (int i = 0; i < 4; ++i) {
            #pragma unroll
            for (int r = 0; r < 4; ++r) {
                const int m = bm0 + wr*64 + i*16 + quad*4 + r;
                const int b = m >> 11, s = m & (S_-1);
                float ss = 0.f;
                #pragma unroll
                for (int j = 0; j < 4; ++j) ss += acc[i][j][r] * acc[i][j][r];
                #pragma unroll
                for (int msk = 1; msk <= 8; msk <<= 1) ss += __shfl_xor(ss, msk, 64);
                const float rn = rsqrtf(ss * (1.0f/64.0f) + 1e-6f);
                #pragma unroll
                for (int j = 0; j < 4; ++j) {
                    const int hd = j*16 + l16;
                    const float nv = acc[i][j][r] * rn * scv[j];
                    const float c  = rope_cos[s*32 + (hd >> 1)];
                    const float sn = rope_sin[s*32 + (hd >> 1)];
                    const float partner = __shfl_xor(nv, 1, 64);
                    const float o = (hd & 1) ? (partner * sn + nv * c) : (nv * c - partner * sn);
                    dst[(((size_t)b*H_ + h)*S_ + s)*HD_ + hd] = f2bf(o * fold);
                }
            }
        }
    } else {
        #pragma unroll
        for (int i = 0; i < 4; ++i)
            #pragma unroll
            for (int r = 0; r < 4; ++r) {
                const int m = bm0 + wr*64 + i*16 + quad*4 + r;
                const int b = m >> 11, s = m & (S_-1);
                #pragma unroll
                for (int j = 0; j < 4; ++j) {
                    const int hd = j*16 + l16;
                    Vt[(((size_t)b*H_ + h)*HD_ + hd)*S_ + s] = f2h(acc[i][j][r]);
                }
            }
    }
}

// ---------------- out-proj GEMM 64x128, BK=64 XOR-swizzled, 2-phase dbuf ----------------
__global__ __launch_bounds__(256)
void gemm_out(const short* __restrict__ po, const float* __restrict__ pl,
              const short* __restrict__ Bw, float* __restrict__ C)
{
    __shared__ __align__(16) short As[2][64*64];    // 2 x 8KB
    __shared__ __align__(16) short Bs[2][128*64];   // 2 x 16KB (total 48KB)
    const int tid = threadIdx.x;
    const int w = tid >> 6, lane = tid & 63, quad = lane >> 4, l16 = lane & 15;
    const int bm0 = blockIdx.x * 64, bn0 = blockIdx.y * 128;

    // B staging (gld16, pre-swizzled global pointers; same scheme as gemm_qkv)
    const int row_ = tid >> 3;
    const int kslot = tid & 7;
    const short* gB[4];
    #pragma unroll
    for (int j = 0; j < 4; ++j) {
        const int row = j*32 + row_;
        const int kch = kslot ^ (row & 7);
        gB[j] = Bw + (size_t)(bn0 + row) * 1024 + kch*8;
    }

    // A production: thread -> row srow, chunks ch0, ch0+1 (8 shorts each)
    const int srow = tid >> 2;          // 0..63
    const int ch0  = (tid & 3) * 2;     // 0,2,4,6
    const int m = bm0 + srow;
    const int b = m >> 11, s = m & (S_-1);
    const short* p0 = po +            (size_t)m * 1024;
    const short* p1 = po + 4194304 + (size_t)m * 1024;

    float inv[16];
    #pragma unroll
    for (int h = 0; h < 16; ++h)
        inv[h] = 1.0f / (pl[((size_t)(b*16 + h))*S_ + s] + pl[65536 + ((size_t)(b*16 + h))*S_ + s]);

    f32x4 acc[4][2];
    #pragma unroll
    for (int i = 0; i < 4; ++i) {
        acc[i][0] = (f32x4){0.f,0.f,0.f,0.f};
        acc[i][1] = (f32x4){0.f,0.f,0.f,0.f};
    }

    // ---- prologue: tile 0 ----
    {
        half8 d00 = *(const half8*)(p0 + ch0*8);
        half8 d01 = *(const half8*)(p1 + ch0*8);
        half8 d10 = *(const half8*)(p0 + ch0*8 + 8);
        half8 d11 = *(const half8*)(p1 + ch0*8 + 8);
        #pragma unroll
        for (int j = 0; j < 4; ++j)
            gld16(gB[j], &Bs[0][j*2048 + w*512]);
        const float invh = inv[0];
        short8 a0, a1;
        #pragma unroll
        for (int j = 0; j < 8; ++j) {
            a0[j] = f2bf(((float)d00[j] + (float)d01[j]) * invh);
            a1[j] = f2bf(((float)d10[j] + (float)d11[j]) * invh);
        }
        *(short8*)(&As[0][srow*64 + (((ch0    ) ^ (srow & 7)) << 3)]) = a0;
        *(short8*)(&As[0][srow*64 + (((ch0 + 1) ^ (srow & 7)) << 3)]) = a1;
        asm volatile("s_waitcnt vmcnt(0) lgkmcnt(0)" ::: "memory");
        __builtin_amdgcn_s_barrier();
        __builtin_amdgcn_sched_barrier(0);
    }

    int cur = 0;
    #pragma unroll
    for (int t = 0; t < 16; ++t) {
        half8 d00, d01, d10, d11;
        if (t < 15) {
            const int k0 = (t + 1) * 64;
            d00 = *(const half8*)(p0 + k0 + ch0*8);
            d01 = *(const half8*)(p1 + k0 + ch0*8);
            d10 = *(const half8*)(p0 + k0 + ch0*8 + 8);
            d11 = *(const half8*)(p1 + k0 + ch0*8 + 8);
            #pragma unroll
            for (int j = 0; j < 4; ++j)
                gld16(gB[j] + k0, &Bs[cur ^ 1][j*2048 + w*512]);
        }
        __builtin_amdgcn_sched_barrier(0);

        #pragma unroll
        for (int ph = 0; ph < 2; ++ph) {
            short8 af[4], bfr[2];
            #pragma unroll
            for (int i = 0; i < 4; ++i) {
                const int ra = i*16 + l16;
                af[i] = *(const short8*)(&As[cur][ra*64 + (((ph*4 + quad) ^ (ra & 7)) << 3)]);
            }
            #pragma unroll
            for (int j = 0; j < 2; ++j) {
                const int rb = w*32 + j*16 + l16;
                bfr[j] = *(const short8*)(&Bs[cur][rb*64 + (((ph*4 + quad) ^ (rb & 7)) << 3)]);
            }
            #pragma unroll
            for (int i = 0; i < 4; ++i)
                #pragma unroll
                for (int j = 0; j < 2; ++j)
                    acc[i][j] = __builtin_amdgcn_mfma_f32_16x16x32_bf16(af[i], bfr[j], acc[i][j], 0, 0, 0);
        }

        if (t < 15) {
            asm volatile("s_waitcnt vmcnt(0)" ::: "memory");
            const float invh = inv[t + 1];
            short8 a0, a1;
            #pragma unroll
            for (int j = 0; j < 8; ++j) {
                a0[j] = f2bf(((float)d00[j] + (float)d01[j]) * invh);
                a1[j] = f2bf(((float)d10[j] + (float)d11[j]) * invh);
            }
            *(short8*)(&As[cur ^ 1][srow*64 + (((ch0    ) ^ (srow & 7)) << 3)]) = a0;
            *(short8*)(&As[cur ^ 1][srow*64 + (((ch0 + 1) ^ (srow & 7)) << 3)]) = a1;
            asm volatile("s_waitcnt lgkmcnt(0)" ::: "memory");
            __builtin_amdgcn_s_barrier();
            __builtin_amdgcn_sched_barrier(0);
            cur ^= 1;
        }
    }

    #pragma unroll
    for (int i = 0; i < 4; ++i)
        #pragma unroll
        for (int r = 0; r < 4; ++r) {
            const int mm = bm0 + i*16 + quad*4 + r;
            #pragma unroll
            for (int j = 0; j < 2; ++j) {
                const int n = bn0 + w*32 + j*16 + l16;
                C[(size_t)mm*1024 + n] = acc[i][j][r];
            }
        }
}

// ---------------- MFMA flash attention partial, split-K=2, XCD-swizzled (R2 config) ----------------
__global__ __launch_bounds__(256)
void flash_mfma(const short* __restrict__ qb, const short* __restrict__ kb,
                const short* __restrict__ vt, short* __restrict__ po, float* __restrict__ pl)
{
    __shared__ __align__(16) short Ks[64*64];
    __shared__ __align__(16) short Vs[64*64];   // f16 bits, [d][key] swizzled

    const int id   = blockIdx.x;
    const int xcd  = id & 7;
    const int rest = id >> 3;
    const int qblk = rest & 15;               // 16 q-blocks of 128
    const int g    = (rest >> 4) * 8 + xcd;   // (bh,sp) group 0..63
    const int bh   = g >> 1;
    const int sp   = g & 1;

    const int tid  = threadIdx.x;
    const int wv   = tid >> 6;
    const int lane = tid & 63;
    const int quad = lane >> 4;
    const int l16  = lane & 15;
    const int b    = bh >> 4, h = bh & (H_-1);
    const int q0   = qblk * 128 + wv * 32;
    const int kt0  = sp * KSPAN_;
    const size_t hbase = (size_t)bh * S_ * HD_;
    const size_t vbase = (size_t)bh * HD_ * S_;
    short* po_sp = po + (size_t)sp * 4194304;
    float* pl_sp = pl + (size_t)sp * 65536;

    const int c0r = tid >> 3,       c0c = tid & 7;
    const int c1r = (tid+256) >> 3, c1c = (tid+256) & 7;

    short8 qfrag[2][2];
    #pragma unroll
    for (int qf = 0; qf < 2; ++qf)
        #pragma unroll
        for (int c = 0; c < 2; ++c)
            qfrag[qf][c] = *(const short8*)(qb + hbase + (size_t)(q0 + qf*16 + l16)*HD_ + c*32 + quad*8);

    f32x4 Oacc[2][4];
    #pragma unroll
    for (int qf = 0; qf < 2; ++qf)
        #pragma unroll
        for (int dt = 0; dt < 4; ++dt) Oacc[qf][dt] = (f32x4){0.f,0.f,0.f,0.f};
    float l_lane[2] = {0.f, 0.f};

    short8 rk0 = *(const short8*)(kb + hbase + (size_t)(kt0 + c0r)*HD_ + c0c*8);
    short8 rk1 = *(const short8*)(kb + hbase + (size_t)(kt0 + c1r)*HD_ + c1c*8);
    short8 rv0 = *(const short8*)(vt + vbase + (size_t)c0r*S_ + kt0 + c0c*8);
    short8 rv1 = *(const short8*)(vt + vbase + (size_t)c1r*S_ + kt0 + c1c*8);

    #pragma unroll 1
    for (int t = 0; t < KSPAN_/64; ++t) {
        __syncthreads();
        *(short8*)(Ks + c0r*64 + ((c0c ^ (c0r & 7)) << 3)) = rk0;
        *(short8*)(Ks + c1r*64 + ((c1c ^ (c1r & 7)) << 3)) = rk1;
        *(short8*)(Vs + c0r*64 + ((c0c ^ (c0r & 7)) << 3)) = rv0;
        *(short8*)(Vs + c1r*64 + ((c1c ^ (c1r & 7)) << 3)) = rv1;
        __syncthreads();
        if (t < KSPAN_/64 - 1) {
            const int ktn = kt0 + (t+1)*64;
            rk0 = *(const short8*)(kb + hbase + (size_t)(ktn + c0r)*HD_ + c0c*8);
            rk1 = *(const short8*)(kb + hbase + (size_t)(ktn + c1r)*HD_ + c1c*8);
            rv0 = *(const short8*)(vt + vbase + (size_t)c0r*S_ + ktn + c0c*8);
            rv1 = *(const short8*)(vt + vbase + (size_t)c1r*S_ + ktn + c1c*8);
        }

        #pragma unroll
        for (int st = 0; st < 4; ++st) {
            short8 kf0 = *(const short8*)(Ks + (st*16 + l16)*64 + (((quad    ) ^ (l16 & 7)) << 3));
            short8 kf1 = *(const short8*)(Ks + (st*16 + l16)*64 + (((4 + quad) ^ (l16 & 7)) << 3));
            const int ch16 = st*2 + (quad >> 1);
            const int sw   = ((ch16 ^ (l16 & 7)) << 3) + (quad & 1)*4;
            half4 va[4];
            #pragma unroll
            for (int dt = 0; dt < 4; ++dt)
                va[dt] = *(const half4*)(Vs + (dt*16 + l16)*64 + sw);
            #pragma unroll
            for (int qf = 0; qf < 2; ++qf) {
                f32x4 acc = (f32x4){0.f,0.f,0.f,0.f};
                acc = __builtin_amdgcn_mfma_f32_16x16x32_bf16(kf0, qfrag[qf][0], acc, 0, 0, 0);
                acc = __builtin_amdgcn_mfma_f32_16x16x32_bf16(kf1, qfrag[qf][1], acc, 0, 0, 0);
                half4 pb;
                #pragma unroll
                for (int r = 0; r < 4; ++r) {
                    float p = __builtin_amdgcn_exp2f(acc[r] - 12.0f);
                    l_lane[qf] += p;
                    pb[r] = (_Float16)p;
                }
                #pragma unroll
                for (int dt = 0; dt < 4; ++dt)
                    Oacc[qf][dt] = __builtin_amdgcn_mfma_f32_16x16x16f16(va[dt], pb, Oacc[qf][dt], 0, 0, 0);
            }
        }
    }

    #pragma unroll
    for (int qf = 0; qf < 2; ++qf) {
        l_lane[qf] += __shfl_xor(l_lane[qf], 16, 64);
        l_lane[qf] += __shfl_xor(l_lane[qf], 32, 64);
        if (quad == 0) pl_sp[(size_t)bh*S_ + q0 + qf*16 + l16] = l_lane[qf];
    }
    #pragma unroll
    for (int qf = 0; qf < 2; ++qf) {
        const int s = q0 + qf*16 + l16;
        #pragma unroll
        for (int dt = 0; dt < 4; ++dt) {
            short4v o;
            #pragma unroll
            for (int r = 0; r < 4; ++r) o[r] = f2h(Oacc[qf][dt][r]);
            *(short4v*)(po_sp + (((size_t)b*S_ + s)*H_ + h)*HD_ + dt*16 + quad*4) = o;
        }
    }
}

extern "C" void kernel_launch(void* const* d_in, const int* in_sizes, int n_in,
                              void* d_out, int out_size, void* d_ws, size_t ws_size,
                              hipStream_t stream)
{
    (void)in_sizes; (void)n_in; (void)out_size; (void)ws_size;
    const float* x        = (const float*)d_in[0];
    const float* wq       = (const float*)d_in[1];
    const float* wk       = (const float*)d_in[2];
    const float* wv       = (const float*)d_in[3];
    const float* wo       = (const float*)d_in[4];
    const float* q_scale  = (const float*)d_in[5];
    const float* k_scale  = (const float*)d_in[6];
    const float* rope_cos = (const float*)d_in[7];
    const float* rope_sin = (const float*)d_in[8];
    float* out = (float*)d_out;
    short* ws  = (short*)d_ws;

    short* qbh   = ws;                 // 4M shorts
    short* kbh   = ws + 4194304;
    short* vt    = ws + 8388608;
    short* xb    = ws + 16777216;
    short* wqkvb = ws + 20971520;      // 3M shorts
    short* wob   = ws + 24117248;      // 1M shorts
    short* po    = ws + 25165824;      // 2 x 4M shorts (f16)
    float* pl    = (float*)(ws + 33554432);  // 2 x 64K floats

    convert_bf16<<<dim3(8192), 256, 0, stream>>>(x, wq, wk, wv, wo, xb, wqkvb, wob);
    gemm_qkv<<<dim3(M_/128, 24), 256, 0, stream>>>(xb, wqkvb, qbh, kbh, vt,
                                                   q_scale, k_scale, rope_cos, rope_sin);
    flash_mfma<<<dim3((S_/128)*B_*H_*SPLIT_), 256, 0, stream>>>(qbh, kbh, vt, po, pl);
    gemm_out<<<dim3(M_/64, D_/128), 256, 0, stream>>>(po, pl, wob, out);
}

// Round 7
// 202.206 us; speedup vs baseline: 1.6624x; 1.0260x over previous
//
#include <hip/hip_runtime.h>
#include <hip/hip_bf16.h>

// RoPEAttention B=2 S=2048 D=1024 H=16 HD=64, fp32 in/out.
// R16: flash Q-block 128->256 (each wave 64 q-rows, qf=0..3). Halves per-unit-
//      work LDS writes, K/V-frag LDS reads, staging VALU, bank conflicts, and
//      L2 K/V re-reads; MFMA unchanged. Grid 1024->512 (2 blocks/CU, 8 waves).
// R15: gemm_out 2-phase dbuf BK=64 (kept). R11: gemm_qkv 2-phase dbuf (kept).
// Flash core = R2-exact staging/prefetch (56.0us measured) with bigger Q-tile.
// ws (shorts): qbh[0,4M) kbh[4M,8M) vt[8M,12M) xb[16M,20M)
//              wqkvb[20M,23M) wob[23M,24M) po[24M,32M) pl(fp32) after.

#define B_ 2
#define S_ 2048
#define D_ 1024
#define H_ 16
#define HD_ 64
#define M_ (B_*S_)
#define SPLIT_ 2
#define KSPAN_ (S_/SPLIT_)    // 1024 keys per split

typedef __attribute__((ext_vector_type(8))) short short8;
typedef __attribute__((ext_vector_type(4))) short short4v;
typedef __attribute__((ext_vector_type(4))) float f32x4;
typedef __attribute__((ext_vector_type(4))) _Float16 half4;
typedef __attribute__((ext_vector_type(8))) _Float16 half8;

static __device__ __forceinline__ short f2bf(float f) {
    __hip_bfloat16 h = __float2bfloat16(f);
    return *reinterpret_cast<short*>(&h);
}
static __device__ __forceinline__ short f2h(float f) {
    _Float16 h = (_Float16)f;
    return *reinterpret_cast<short*>(&h);
}

typedef __attribute__((address_space(1))) const unsigned int gu32_t;
typedef __attribute__((address_space(3))) unsigned int lu32_t;
static __device__ __forceinline__ void gld16(const short* g, short* l) {
    __builtin_amdgcn_global_load_lds((gu32_t*)g, (lu32_t*)l, 16, 0, 0);
}

// ---------------- fp32 -> bf16 convert: x, wq|wk|wv (concat), wo ----------------
__global__ __launch_bounds__(256)
void convert_bf16(const float* __restrict__ x,
                  const float* __restrict__ wq, const float* __restrict__ wk,
                  const float* __restrict__ wv, const float* __restrict__ wo,
                  short* __restrict__ xb, short* __restrict__ wqkvb, short* __restrict__ wob)
{
    const size_t t4 = ((size_t)blockIdx.x * 256 + threadIdx.x) * 4;
    const float* src; short* dst; size_t off, doff;
    if (t4 < 4194304)      { src = x;  dst = xb;    off = t4;           doff = t4; }
    else if (t4 < 5242880) { src = wq; dst = wqkvb; off = t4 - 4194304; doff = t4 - 4194304; }
    else if (t4 < 6291456) { src = wk; dst = wqkvb; off = t4 - 5242880; doff = t4 - 4194304; }
    else if (t4 < 7340032) { src = wv; dst = wqkvb; off = t4 - 6291456; doff = t4 - 4194304; }
    else                   { src = wo; dst = wob;   off = t4 - 7340032; doff = t4 - 7340032; }
    float4 v = *(const float4*)(src + off);
    short4v s = { f2bf(v.x), f2bf(v.y), f2bf(v.z), f2bf(v.w) };
    *(short4v*)(dst + doff) = s;
}

// ---------------- bf16 MFMA GEMM NT 128x128, BK=64 XOR-swizzled, 2-phase dbuf ----------------
// Epilogue: which==0/1 -> fused RMSNorm+RoPE -> Qb/Kb bf16 [B,H,S,HD]
//           which==2   -> Vt f16 [B,H,HD,S]
__global__ __launch_bounds__(256)
void gemm_qkv(const short* __restrict__ A, const short* __restrict__ Bw,
              short* __restrict__ Qb, short* __restrict__ Kb, short* __restrict__ Vt,
              const float* __restrict__ q_scale, const float* __restrict__ k_scale,
              const float* __restrict__ rope_cos, const float* __restrict__ rope_sin)
{
    __shared__ __align__(16) short As[2][128*64];   // 2 x 16KB
    __shared__ __align__(16) short Bs[2][128*64];   // 2 x 16KB  (total 64KB)
    const int tid = threadIdx.x;
    const int w = tid >> 6, lane = tid & 63, quad = lane >> 4, l16 = lane & 15;
    const int wr = w >> 1, wc = w & 1;
    const int bm0 = blockIdx.x * 128, bn0 = blockIdx.y * 128;

    const int row_ = tid >> 3;
    const int kslot = tid & 7;
    const short* gA[4]; const short* gB[4];
    #pragma unroll
    for (int j = 0; j < 4; ++j) {
        const int row = j*32 + row_;
        const int kch = kslot ^ (row & 7);
        gA[j] = A  + (size_t)(bm0 + row) * 1024 + kch*8;
        gB[j] = Bw + (size_t)(bn0 + row) * 1024 + kch*8;
    }

    f32x4 acc[4][4];
    #pragma unroll
    for (int i = 0; i < 4; ++i)
        #pragma unroll
        for (int j = 0; j < 4; ++j) acc[i][j] = (f32x4){0.f,0.f,0.f,0.f};

    // prologue: stage K-tile 0 into buffer 0, drain, barrier
    #pragma unroll
    for (int j = 0; j < 4; ++j) {
        gld16(gA[j], &As[0][j*2048 + w*512]);
        gld16(gB[j], &Bs[0][j*2048 + w*512]);
    }
    asm volatile("s_waitcnt vmcnt(0)" ::: "memory");
    __builtin_amdgcn_s_barrier();
    __builtin_amdgcn_sched_barrier(0);

    int cur = 0;
    for (int t = 0; t < 16; ++t) {
        if (t < 15) {
            const int k0 = (t + 1) * 64;
            #pragma unroll
            for (int j = 0; j < 4; ++j) {
                gld16(gA[j] + k0, &As[cur ^ 1][j*2048 + w*512]);
                gld16(gB[j] + k0, &Bs[cur ^ 1][j*2048 + w*512]);
            }
        }
        __builtin_amdgcn_sched_barrier(0);

        short8 af[2][4], bfr[2][4];
        #pragma unroll
        for (int ph = 0; ph < 2; ++ph)
            #pragma unroll
            for (int i = 0; i < 4; ++i) {
                const int ra = wr*64 + i*16 + l16;
                af[ph][i]  = *(const short8*)(&As[cur][ra*64 + (((ph*4 + quad) ^ (ra & 7)) << 3)]);
                const int rb = wc*64 + i*16 + l16;
                bfr[ph][i] = *(const short8*)(&Bs[cur][rb*64 + (((ph*4 + quad) ^ (rb & 7)) << 3)]);
            }
        #pragma unroll
        for (int ph = 0; ph < 2; ++ph)
            #pragma unroll
            for (int i = 0; i < 4; ++i)
                #pragma unroll
                for (int j = 0; j < 4; ++j)
                    acc[i][j] = __builtin_amdgcn_mfma_f32_16x16x32_bf16(af[ph][i], bfr[ph][j], acc[i][j], 0, 0, 0);

        asm volatile("s_waitcnt vmcnt(0)" ::: "memory");
        __builtin_amdgcn_s_barrier();
        __builtin_amdgcn_sched_barrier(0);
        cur ^= 1;
    }

    const int nbase = bn0 + wc*64;
    const int which = nbase >> 10;
    const int h     = (nbase & 1023) >> 6;

    if (which < 2) {
        const float* sc = which ? k_scale : q_scale;
        short* dst      = which ? Kb : Qb;
        const float fold = which ? 1.0f : 0.18033688011112042f;  // q: (1/8)*log2(e)
        float scv[4];
        #pragma unroll
        for (int j = 0; j < 4; ++j) scv[j] = sc[j*16 + l16];
        #pragma unroll
        for (int i = 0; i < 4; ++i) {
            #pragma unroll
            for (int r = 0; r < 4; ++r) {
                const int m = bm0 + wr*64 + i*16 + quad*4 + r;
                const int b = m >> 11, s = m & (S_-1);
                float ss = 0.f;
                #pragma unroll
                for (int j = 0; j < 4; ++j) ss += acc[i][j][r] * acc[i][j][r];
                #pragma unroll
                for (int msk = 1; msk <= 8; msk <<= 1) ss += __shfl_xor(ss, msk, 64);
                const float rn = rsqrtf(ss * (1.0f/64.0f) + 1e-6f);
                #pragma unroll
                for (int j = 0; j < 4; ++j) {
                    const int hd = j*16 + l16;
                    const float nv = acc[i][j][r] * rn * scv[j];
                    const float c  = rope_cos[s*32 + (hd >> 1)];
                    const float sn = rope_sin[s*32 + (hd >> 1)];
                    const float partner = __shfl_xor(nv, 1, 64);
                    const float o = (hd & 1) ? (partner * sn + nv * c) : (nv * c - partner * sn);
                    dst[(((size_t)b*H_ + h)*S_ + s)*HD_ + hd] = f2bf(o * fold);
                }
            }
        }
    } else {
        #pragma unroll
        for (int i = 0; i < 4; ++i)
            #pragma unroll
            for (int r = 0; r < 4; ++r) {
                const int m = bm0 + wr*64 + i*16 + quad*4 + r;
                const int b = m >> 11, s = m & (S_-1);
                #pragma unroll
                for (int j = 0; j < 4; ++j) {
                    const int hd = j*16 + l16;
                    Vt[(((size_t)b*H_ + h)*HD_ + hd)*S_ + s] = f2h(acc[i][j][r]);
                }
            }
    }
}

// ---------------- out-proj GEMM 64x128, BK=64 XOR-swizzled, 2-phase dbuf ----------------
__global__ __launch_bounds__(256)
void gemm_out(const short* __restrict__ po, const float* __restrict__ pl,
              const short* __restrict__ Bw, float* __restrict__ C)
{
    __shared__ __align__(16) short As[2][64*64];    // 2 x 8KB
    __shared__ __align__(16) short Bs[2][128*64];   // 2 x 16KB (total 48KB)
    const int tid = threadIdx.x;
    const int w = tid >> 6, lane = tid & 63, quad = lane >> 4, l16 = lane & 15;
    const int bm0 = blockIdx.x * 64, bn0 = blockIdx.y * 128;

    // B staging (gld16, pre-swizzled global pointers; same scheme as gemm_qkv)
    const int row_ = tid >> 3;
    const int kslot = tid & 7;
    const short* gB[4];
    #pragma unroll
    for (int j = 0; j < 4; ++j) {
        const int row = j*32 + row_;
        const int kch = kslot ^ (row & 7);
        gB[j] = Bw + (size_t)(bn0 + row) * 1024 + kch*8;
    }

    // A production: thread -> row srow, chunks ch0, ch0+1 (8 shorts each)
    const int srow = tid >> 2;          // 0..63
    const int ch0  = (tid & 3) * 2;     // 0,2,4,6
    const int m = bm0 + srow;
    const int b = m >> 11, s = m & (S_-1);
    const short* p0 = po +            (size_t)m * 1024;
    const short* p1 = po + 4194304 + (size_t)m * 1024;

    float inv[16];
    #pragma unroll
    for (int h = 0; h < 16; ++h)
        inv[h] = 1.0f / (pl[((size_t)(b*16 + h))*S_ + s] + pl[65536 + ((size_t)(b*16 + h))*S_ + s]);

    f32x4 acc[4][2];
    #pragma unroll
    for (int i = 0; i < 4; ++i) {
        acc[i][0] = (f32x4){0.f,0.f,0.f,0.f};
        acc[i][1] = (f32x4){0.f,0.f,0.f,0.f};
    }

    // ---- prologue: tile 0 ----
    {
        half8 d00 = *(const half8*)(p0 + ch0*8);
        half8 d01 = *(const half8*)(p1 + ch0*8);
        half8 d10 = *(const half8*)(p0 + ch0*8 + 8);
        half8 d11 = *(const half8*)(p1 + ch0*8 + 8);
        #pragma unroll
        for (int j = 0; j < 4; ++j)
            gld16(gB[j], &Bs[0][j*2048 + w*512]);
        const float invh = inv[0];
        short8 a0, a1;
        #pragma unroll
        for (int j = 0; j < 8; ++j) {
            a0[j] = f2bf(((float)d00[j] + (float)d01[j]) * invh);
            a1[j] = f2bf(((float)d10[j] + (float)d11[j]) * invh);
        }
        *(short8*)(&As[0][srow*64 + (((ch0    ) ^ (srow & 7)) << 3)]) = a0;
        *(short8*)(&As[0][srow*64 + (((ch0 + 1) ^ (srow & 7)) << 3)]) = a1;
        asm volatile("s_waitcnt vmcnt(0) lgkmcnt(0)" ::: "memory");
        __builtin_amdgcn_s_barrier();
        __builtin_amdgcn_sched_barrier(0);
    }

    int cur = 0;
    #pragma unroll
    for (int t = 0; t < 16; ++t) {
        half8 d00, d01, d10, d11;
        if (t < 15) {
            const int k0 = (t + 1) * 64;
            d00 = *(const half8*)(p0 + k0 + ch0*8);
            d01 = *(const half8*)(p1 + k0 + ch0*8);
            d10 = *(const half8*)(p0 + k0 + ch0*8 + 8);
            d11 = *(const half8*)(p1 + k0 + ch0*8 + 8);
            #pragma unroll
            for (int j = 0; j < 4; ++j)
                gld16(gB[j] + k0, &Bs[cur ^ 1][j*2048 + w*512]);
        }
        __builtin_amdgcn_sched_barrier(0);

        #pragma unroll
        for (int ph = 0; ph < 2; ++ph) {
            short8 af[4], bfr[2];
            #pragma unroll
            for (int i = 0; i < 4; ++i) {
                const int ra = i*16 + l16;
                af[i] = *(const short8*)(&As[cur][ra*64 + (((ph*4 + quad) ^ (ra & 7)) << 3)]);
            }
            #pragma unroll
            for (int j = 0; j < 2; ++j) {
                const int rb = w*32 + j*16 + l16;
                bfr[j] = *(const short8*)(&Bs[cur][rb*64 + (((ph*4 + quad) ^ (rb & 7)) << 3)]);
            }
            #pragma unroll
            for (int i = 0; i < 4; ++i)
                #pragma unroll
                for (int j = 0; j < 2; ++j)
                    acc[i][j] = __builtin_amdgcn_mfma_f32_16x16x32_bf16(af[i], bfr[j], acc[i][j], 0, 0, 0);
        }

        if (t < 15) {
            asm volatile("s_waitcnt vmcnt(0)" ::: "memory");
            const float invh = inv[t + 1];
            short8 a0, a1;
            #pragma unroll
            for (int j = 0; j < 8; ++j) {
                a0[j] = f2bf(((float)d00[j] + (float)d01[j]) * invh);
                a1[j] = f2bf(((float)d10[j] + (float)d11[j]) * invh);
            }
            *(short8*)(&As[cur ^ 1][srow*64 + (((ch0    ) ^ (srow & 7)) << 3)]) = a0;
            *(short8*)(&As[cur ^ 1][srow*64 + (((ch0 + 1) ^ (srow & 7)) << 3)]) = a1;
            asm volatile("s_waitcnt lgkmcnt(0)" ::: "memory");
            __builtin_amdgcn_s_barrier();
            __builtin_amdgcn_sched_barrier(0);
            cur ^= 1;
        }
    }

    #pragma unroll
    for (int i = 0; i < 4; ++i)
        #pragma unroll
        for (int r = 0; r < 4; ++r) {
            const int mm = bm0 + i*16 + quad*4 + r;
            #pragma unroll
            for (int j = 0; j < 2; ++j) {
                const int n = bn0 + w*32 + j*16 + l16;
                C[(size_t)mm*1024 + n] = acc[i][j][r];
            }
        }
}

// ---------------- MFMA flash attention partial, split-K=2, XCD-swizzled, Q-block 256 ----------------
__global__ __launch_bounds__(256)
void flash_mfma(const short* __restrict__ qb, const short* __restrict__ kb,
                const short* __restrict__ vt, short* __restrict__ po, float* __restrict__ pl)
{
    __shared__ __align__(16) short Ks[64*64];
    __shared__ __align__(16) short Vs[64*64];   // f16 bits, [d][key] swizzled

    const int id   = blockIdx.x;
    const int xcd  = id & 7;
    const int rest = id >> 3;
    const int qblk = rest & 7;                // 8 q-blocks of 256
    const int g    = (rest >> 3) * 8 + xcd;   // (bh,sp) group 0..63
    const int bh   = g >> 1;
    const int sp   = g & 1;

    const int tid  = threadIdx.x;
    const int wv   = tid >> 6;
    const int lane = tid & 63;
    const int quad = lane >> 4;
    const int l16  = lane & 15;
    const int b    = bh >> 4, h = bh & (H_-1);
    const int q0   = qblk * 256 + wv * 64;    // 64 q-rows per wave
    const int kt0  = sp * KSPAN_;
    const size_t hbase = (size_t)bh * S_ * HD_;
    const size_t vbase = (size_t)bh * HD_ * S_;
    short* po_sp = po + (size_t)sp * 4194304;
    float* pl_sp = pl + (size_t)sp * 65536;

    const int c0r = tid >> 3,       c0c = tid & 7;
    const int c1r = (tid+256) >> 3, c1c = (tid+256) & 7;

    short8 qfrag[4][2];
    #pragma unroll
    for (int qf = 0; qf < 4; ++qf)
        #pragma unroll
        for (int c = 0; c < 2; ++c)
            qfrag[qf][c] = *(const short8*)(qb + hbase + (size_t)(q0 + qf*16 + l16)*HD_ + c*32 + quad*8);

    f32x4 Oacc[4][4];
    #pragma unroll
    for (int qf = 0; qf < 4; ++qf)
        #pragma unroll
        for (int dt = 0; dt < 4; ++dt) Oacc[qf][dt] = (f32x4){0.f,0.f,0.f,0.f};
    float l_lane[4] = {0.f, 0.f, 0.f, 0.f};

    short8 rk0 = *(const short8*)(kb + hbase + (size_t)(kt0 + c0r)*HD_ + c0c*8);
    short8 rk1 = *(const short8*)(kb + hbase + (size_t)(kt0 + c1r)*HD_ + c1c*8);
    short8 rv0 = *(const short8*)(vt + vbase + (size_t)c0r*S_ + kt0 + c0c*8);
    short8 rv1 = *(const short8*)(vt + vbase + (size_t)c1r*S_ + kt0 + c1c*8);

    #pragma unroll 1
    for (int t = 0; t < KSPAN_/64; ++t) {
        __syncthreads();
        *(short8*)(Ks + c0r*64 + ((c0c ^ (c0r & 7)) << 3)) = rk0;
        *(short8*)(Ks + c1r*64 + ((c1c ^ (c1r & 7)) << 3)) = rk1;
        *(short8*)(Vs + c0r*64 + ((c0c ^ (c0r & 7)) << 3)) = rv0;
        *(short8*)(Vs + c1r*64 + ((c1c ^ (c1r & 7)) << 3)) = rv1;
        __syncthreads();
        if (t < KSPAN_/64 - 1) {
            const int ktn = kt0 + (t+1)*64;
            rk0 = *(const short8*)(kb + hbase + (size_t)(ktn + c0r)*HD_ + c0c*8);
            rk1 = *(const short8*)(kb + hbase + (size_t)(ktn + c1r)*HD_ + c1c*8);
            rv0 = *(const short8*)(vt + vbase + (size_t)c0r*S_ + ktn + c0c*8);
            rv1 = *(const short8*)(vt + vbase + (size_t)c1r*S_ + ktn + c1c*8);
        }

        #pragma unroll
        for (int st = 0; st < 4; ++st) {
            short8 kf0 = *(const short8*)(Ks + (st*16 + l16)*64 + (((quad    ) ^ (l16 & 7)) << 3));
            short8 kf1 = *(const short8*)(Ks + (st*16 + l16)*64 + (((4 + quad) ^ (l16 & 7)) << 3));
            const int ch16 = st*2 + (quad >> 1);
            const int sw   = ((ch16 ^ (l16 & 7)) << 3) + (quad & 1)*4;
            half4 va[4];
            #pragma unroll
            for (int dt = 0; dt < 4; ++dt)
                va[dt] = *(const half4*)(Vs + (dt*16 + l16)*64 + sw);
            #pragma unroll
            for (int qf = 0; qf < 4; ++qf) {
                f32x4 acc = (f32x4){0.f,0.f,0.f,0.f};
                acc = __builtin_amdgcn_mfma_f32_16x16x32_bf16(kf0, qfrag[qf][0], acc, 0, 0, 0);
                acc = __builtin_amdgcn_mfma_f32_16x16x32_bf16(kf1, qfrag[qf][1], acc, 0, 0, 0);
                half4 pb;
                #pragma unroll
                for (int r = 0; r < 4; ++r) {
                    float p = __builtin_amdgcn_exp2f(acc[r] - 12.0f);
                    l_lane[qf] += p;
                    pb[r] = (_Float16)p;
                }
                #pragma unroll
                for (int dt = 0; dt < 4; ++dt)
                    Oacc[qf][dt] = __builtin_amdgcn_mfma_f32_16x16x16f16(va[dt], pb, Oacc[qf][dt], 0, 0, 0);
            }
        }
    }

    #pragma unroll
    for (int qf = 0; qf < 4; ++qf) {
        l_lane[qf] += __shfl_xor(l_lane[qf], 16, 64);
        l_lane[qf] += __shfl_xor(l_lane[qf], 32, 64);
        if (quad == 0) pl_sp[(size_t)bh*S_ + q0 + qf*16 + l16] = l_lane[qf];
    }
    #pragma unroll
    for (int qf = 0; qf < 4; ++qf) {
        const int s = q0 + qf*16 + l16;
        #pragma unroll
        for (int dt = 0; dt < 4; ++dt) {
            short4v o;
            #pragma unroll
            for (int r = 0; r < 4; ++r) o[r] = f2h(Oacc[qf][dt][r]);
            *(short4v*)(po_sp + (((size_t)b*S_ + s)*H_ + h)*HD_ + dt*16 + quad*4) = o;
        }
    }
}

extern "C" void kernel_launch(void* const* d_in, const int* in_sizes, int n_in,
                              void* d_out, int out_size, void* d_ws, size_t ws_size,
                              hipStream_t stream)
{
    (void)in_sizes; (void)n_in; (void)out_size; (void)ws_size;
    const float* x        = (const float*)d_in[0];
    const float* wq       = (const float*)d_in[1];
    const float* wk       = (const float*)d_in[2];
    const float* wv       = (const float*)d_in[3];
    const float* wo       = (const float*)d_in[4];
    const float* q_scale  = (const float*)d_in[5];
    const float* k_scale  = (const float*)d_in[6];
    const float* rope_cos = (const float*)d_in[7];
    const float* rope_sin = (const float*)d_in[8];
    float* out = (float*)d_out;
    short* ws  = (short*)d_ws;

    short* qbh   = ws;                 // 4M shorts
    short* kbh   = ws + 4194304;
    short* vt    = ws + 8388608;
    short* xb    = ws + 16777216;
    short* wqkvb = ws + 20971520;      // 3M shorts
    short* wob   = ws + 24117248;      // 1M shorts
    short* po    = ws + 25165824;      // 2 x 4M shorts (f16)
    float* pl    = (float*)(ws + 33554432);  // 2 x 64K floats

    convert_bf16<<<dim3(8192), 256, 0, stream>>>(x, wq, wk, wv, wo, xb, wqkvb, wob);
    gemm_qkv<<<dim3(M_/128, 24), 256, 0, stream>>>(xb, wqkvb, qbh, kbh, vt,
                                                   q_scale, k_scale, rope_cos, rope_sin);
    flash_mfma<<<dim3((S_/256)*B_*H_*SPLIT_), 256, 0, stream>>>(qbh, kbh, vt, po, pl);
    gemm_out<<<dim3(M_/64, D_/128), 256, 0, stream>>>(po, pl, wob, out);
}